// Round 2
// baseline (469.774 us; speedup 1.0000x reference)
//
#include <hip/hip_runtime.h>
#include <stdint.h>

#define NCLS 80
#define BATCH 8
#define NA 20460          // total anchors per image across 5 levels
#define TOPK 1000
#define MAXPER 100
#define IMG_WF 1280.0f
#define IMG_HF 768.0f
#define CLS_OFF 4096.0f
#define MAX_RATIO_ANCHOR 13.815510557964274f  // |log(1e-6)|
#define MAX_RATIO_BBOX   4.1351665567423557f  // |log(16/1000)|

__constant__ int   c_lvoff[6] = {0, 15360, 19200, 20160, 20400, 20460};
__constant__ int   c_lw[5]    = {160, 80, 40, 20, 10};
__constant__ int   c_lh[5]    = {96, 48, 24, 12, 6};
__constant__ float c_ls[5]    = {8.f, 16.f, 32.f, 64.f, 128.f};

struct InPtrs {
  const float* cls[5];
  const float* bbox[5];
  const float* shp[5];
  const float* loc[5];
};

__device__ __forceinline__ float sigf(float x) { return 1.0f / (1.0f + expf(-x)); }

// ---------------- K1: per-anchor max score (mask applied) ----------------
__global__ __launch_bounds__(256) void k_maxscore(InPtrs P, float* maxscore) {
  int gid = blockIdx.x * 256 + threadIdx.x;
  if (gid >= BATCH * NA) return;
  int b = gid / NA;
  int a = gid - b * NA;
  int l = 0;
  while (a >= c_lvoff[l + 1]) ++l;
  int within = a - c_lvoff[l];
  int W = c_lw[l], H = c_lh[l];
  int hw = H * W;
  int sp = within;
  const float* cls = P.cls[l];
  int base = (b * NCLS) * hw + sp;
  float m = -1e30f;
  for (int c = 0; c < NCLS; ++c) m = fmaxf(m, cls[base + c * hw]);
  float sl = sigf(P.loc[l][b * hw + sp]);
  float score = 0.0f;
  if (sl >= 0.01f) {
    score = sigf(sigf(m));  // monotone: max over double-sigmoid == double-sigmoid of max
  }
  maxscore[gid] = score;
}

// ---------------- K2: exact top-1000 per batch, in top_k order ----------------
// Binary search on float bit patterns for the boundary value V, then collect
// (>V arbitrary order, ==V ascending index) and bitonic-sort 1024 keys by
// (score desc, anchor asc) — exactly the reference's two-stage top_k row order.
__global__ __launch_bounds__(1024) void k_select(const float* maxscore, int* sel) {
  int b = blockIdx.x;
  const unsigned int* ms = (const unsigned int*)(maxscore + (size_t)b * NA);
  int tid = threadIdx.x;
  __shared__ int s_part[16];
  __shared__ int s_bcast;
  __shared__ int s_pos;
  __shared__ int s_scan[1024];
  __shared__ unsigned long long s_keys[1024];

  // all scores >= 0 so uint order == float order; scores < 1.0 always.
  unsigned int lo = 0u, hi = 0x3F800000u;  // cnt(lo)=NA>=1000 ; cnt(1.0f)=0<1000
  while (hi - lo > 1u) {
    unsigned int mid = lo + (hi - lo) / 2u;
    int c = 0;
    for (int i = tid; i < NA; i += 1024) c += (ms[i] >= mid) ? 1 : 0;
    #pragma unroll
    for (int o = 32; o > 0; o >>= 1) c += __shfl_down(c, o, 64);
    if ((tid & 63) == 0) s_part[tid >> 6] = c;
    __syncthreads();
    if (tid == 0) {
      int t = 0;
      for (int w = 0; w < 16; ++w) t += s_part[w];
      s_bcast = t;
    }
    __syncthreads();
    if (s_bcast >= TOPK) lo = mid; else hi = mid;
    __syncthreads();
  }
  unsigned int V = lo;  // bit pattern of the 1000th-largest value

  if (tid == 0) s_pos = 0;
  if (tid < 1024 - TOPK) s_keys[TOPK + tid] = 0ull;  // pads sink to the end
  __syncthreads();
  for (int i = tid; i < NA; i += 1024) {
    unsigned int v = ms[i];
    if (v > V) {
      int p = atomicAdd(&s_pos, 1);
      s_keys[p] = ((unsigned long long)v << 32) |
                  (unsigned long long)(0xFFFFFFFFu - (unsigned)i);
    }
  }
  __syncthreads();
  int ngt = s_pos;
  int need = TOPK - ngt;  // >= 1; filled by ==V in ascending index order
  const int CH = (NA + 1023) / 1024;  // 20
  int i0 = tid * CH, i1 = min(i0 + CH, NA);
  int ceq = 0;
  for (int i = i0; i < i1; ++i) ceq += (ms[i] == V) ? 1 : 0;
  s_scan[tid] = ceq;
  __syncthreads();
  for (int o = 1; o < 1024; o <<= 1) {
    int v = s_scan[tid];
    int add = (tid >= o) ? s_scan[tid - o] : 0;
    __syncthreads();
    s_scan[tid] = v + add;
    __syncthreads();
  }
  int r = s_scan[tid] - ceq;  // exclusive prefix = rank of my first ==V element
  for (int i = i0; i < i1 && r < need; ++i) {
    if (ms[i] == V) {
      s_keys[ngt + r] = ((unsigned long long)V << 32) |
                        (unsigned long long)(0xFFFFFFFFu - (unsigned)i);
      ++r;
    }
  }
  __syncthreads();

  // bitonic sort 1024 keys, descending (score desc, then anchor index asc)
  for (unsigned int k = 2; k <= 1024; k <<= 1) {
    for (unsigned int j = k >> 1; j > 0; j >>= 1) {
      unsigned int i = (unsigned int)tid;
      unsigned int l = i ^ j;
      if (l > i) {
        unsigned long long a = s_keys[i], bk = s_keys[l];
        bool swap = ((i & k) == 0) ? (a < bk) : (a > bk);
        if (swap) { s_keys[i] = bk; s_keys[l] = a; }
      }
      __syncthreads();
    }
  }
  if (tid < TOPK) {
    sel[b * TOPK + tid] = (int)(0xFFFFFFFFu - (unsigned)(s_keys[tid] & 0xFFFFFFFFull));
  }
}

// ---------------- K3: decode boxes + 80 class scores for selected rows ----------------
__global__ __launch_bounds__(256) void k_gather(InPtrs P, const int* sel, float* boxes, float* sv) {
  int gid = blockIdx.x * 256 + threadIdx.x;
  if (gid >= BATCH * TOPK) return;
  int b = gid / TOPK;
  int r = gid - b * TOPK;
  int a = sel[b * TOPK + r];
  int l = 0;
  while (a >= c_lvoff[l + 1]) ++l;
  int within = a - c_lvoff[l];
  int W = c_lw[l], H = c_lh[l];
  int y = within / W, x = within - y * W;
  int hw = H * W;
  int sp = within;
  float stride = c_ls[l];
  float px = (float)x * stride;   // exact (square anchor center)
  float py = (float)y * stride;
  float pw = 4.0f * stride;       // octave_scale * stride, exact

  // guided anchor from shape_pred (delta2bbox, dx=dy=0, no clip)
  const float* shp = P.shp[l];
  float dws = shp[(b * 2 + 0) * hw + sp];
  float dhs = shp[(b * 2 + 1) * hw + sp];
  dws = fminf(fmaxf(dws, -MAX_RATIO_ANCHOR), MAX_RATIO_ANCHOR);
  dhs = fminf(fmaxf(dhs, -MAX_RATIO_ANCHOR), MAX_RATIO_ANCHOR);
  float gw = pw * expf(dws);
  float gh = pw * expf(dhs);
  float ax1 = px - 0.5f * gw, ax2 = px + 0.5f * gw;
  float ay1 = py - 0.5f * gh, ay2 = py + 0.5f * gh;

  // proposal from bbox_pred (delta2bbox with image clip)
  const float* bb = P.bbox[l];
  float dx = bb[(b * 4 + 0) * hw + sp];
  float dy = bb[(b * 4 + 1) * hw + sp];
  float dw = bb[(b * 4 + 2) * hw + sp];
  float dh = bb[(b * 4 + 3) * hw + sp];
  dw = fminf(fmaxf(dw, -MAX_RATIO_BBOX), MAX_RATIO_BBOX);
  dh = fminf(fmaxf(dh, -MAX_RATIO_BBOX), MAX_RATIO_BBOX);
  float px2 = (ax1 + ax2) * 0.5f, py2 = (ay1 + ay2) * 0.5f;
  float pw2 = ax2 - ax1, ph2 = ay2 - ay1;
  float gx = px2 + pw2 * dx, gy = py2 + ph2 * dy;
  float gw2 = pw2 * expf(dw), gh2 = ph2 * expf(dh);
  float x1 = fminf(fmaxf(gx - 0.5f * gw2, 0.0f), IMG_WF);
  float x2 = fminf(fmaxf(gx + 0.5f * gw2, 0.0f), IMG_WF);
  float y1 = fminf(fmaxf(gy - 0.5f * gh2, 0.0f), IMG_HF);
  float y2 = fminf(fmaxf(gy + 0.5f * gh2, 0.0f), IMG_HF);
  float* bo = boxes + ((size_t)(b * TOPK + r)) * 4;
  bo[0] = x1; bo[1] = y1; bo[2] = x2; bo[3] = y2;

  // scores (class-major layout for NMS column access)
  const float* cls = P.cls[l];
  float sl = sigf(P.loc[l][b * hw + sp]);
  bool mask = (sl >= 0.01f);
  int base = (b * NCLS) * hw + sp;
  for (int c = 0; c < NCLS; ++c) {
    float v = 0.0f;
    if (mask) {
      float s2 = sigf(sigf(cls[base + c * hw]));
      v = (s2 > 0.05f) ? s2 : 0.0f;   // SCORE_THR (strict >)
    }
    sv[((size_t)(b * NCLS + c)) * TOPK + r] = v;
  }
}

// ---------------- K4: per-(batch,class) greedy NMS, all in LDS ----------------
// kc output: +kept normally; -kept when the stream ends in an infinitely
// repeating degenerate pick (zero/tiny-area box that fails to self-suppress).
__global__ __launch_bounds__(256) void k_nms(const float* boxes, const float* sv,
                                             float* keptScore, int* keptRow, int* kc) {
  int bc = blockIdx.x;              // 0..639
  int b = bc / NCLS;
  int c = bc - b * NCLS;
  int tid = threadIdx.x;
  __shared__ float s_x1[TOPK], s_y1[TOPK], s_x2[TOPK], s_y2[TOPK], s_ar[TOPK];
  __shared__ float s_sc[1024];
  __shared__ unsigned long long s_part[4];
  __shared__ unsigned long long s_best;

  float off = (float)c * CLS_OFF;   // exact in f32
  for (int i = tid; i < TOPK; i += 256) {
    const float* bo = boxes + ((size_t)(b * TOPK + i)) * 4;
    // reference computes IoU/areas on OFFSET coords (f32-rounded) — replicate
    float x1 = bo[0] + off, y1 = bo[1] + off, x2 = bo[2] + off, y2 = bo[3] + off;
    s_x1[i] = x1; s_y1[i] = y1; s_x2[i] = x2; s_y2[i] = y2;
    s_ar[i] = (x2 - x1) * (y2 - y1);
    s_sc[i] = sv[((size_t)(b * NCLS + c)) * TOPK + i];
  }
  for (int i = TOPK + tid; i < 1024; i += 256) s_sc[i] = 0.0f;
  __syncthreads();

  int kept = 0;
  bool sticky = false;
  float* ks = keptScore + (size_t)(b * NCLS + c) * MAXPER;
  int*   kr = keptRow   + (size_t)(b * NCLS + c) * MAXPER;
  for (int iter = 0; iter < MAXPER; ++iter) {
    // argmax (tie -> lower row, matching flat-argmax semantics in sorted row order)
    unsigned long long key = 0ull;
    #pragma unroll
    for (int j = 0; j < 4; ++j) {
      int idx = tid + j * 256;
      float s = s_sc[idx];
      unsigned long long k = ((unsigned long long)__float_as_uint(s) << 32) |
                             (unsigned long long)(0xFFFFFFFFu - (unsigned)idx);
      key = (k > key) ? k : key;
    }
    #pragma unroll
    for (int o = 32; o > 0; o >>= 1) {
      unsigned long long other = __shfl_xor(key, o, 64);
      key = (other > key) ? other : key;
    }
    if ((tid & 63) == 0) s_part[tid >> 6] = key;
    __syncthreads();
    if (tid == 0) {
      unsigned long long bk = s_part[0];
      for (int w = 1; w < 4; ++w) bk = (s_part[w] > bk) ? s_part[w] : bk;
      s_best = bk;
    }
    __syncthreads();
    unsigned long long bk = s_best;
    float bs = __uint_as_float((unsigned)(bk >> 32));
    if (bs <= 0.0f) break;   // uniform
    int bi = (int)(0xFFFFFFFFu - (unsigned)(bk & 0xFFFFFFFFull));
    if (tid == 0) { ks[kept] = bs; kr[kept] = bi; }
    kept++;
    float bx1 = s_x1[bi], by1 = s_y1[bi], bx2 = s_x2[bi], by2 = s_y2[bi], ba = s_ar[bi];
    #pragma unroll
    for (int j = 0; j < 4; ++j) {
      int idx = tid + j * 256;
      if (idx < TOPK) {
        float ltx = fmaxf(bx1, s_x1[idx]);
        float lty = fmaxf(by1, s_y1[idx]);
        float rbx = fminf(bx2, s_x2[idx]);
        float rby = fminf(by2, s_y2[idx]);
        float w = fmaxf(rbx - ltx, 0.0f);
        float h = fmaxf(rby - lty, 0.0f);
        float inter = w * h;
        float iou = inter / (ba + s_ar[idx] - inter + 1e-6f);
        if (iou > 0.5f) s_sc[idx] = 0.0f;
      }
    }
    __syncthreads();
    // Degenerate check: if the pick did NOT self-suppress (zero/tiny area,
    // self-IoU <= 0.5), the reference scan re-picks it forever. The class
    // stream from here on is an infinite repeat of this entry.
    if (s_sc[bi] > 0.0f) {    // uniform read of one LDS word
      for (int k2 = kept + tid; k2 < MAXPER; k2 += 256) { ks[k2] = bs; kr[k2] = bi; }
      kept = MAXPER;
      sticky = true;
      break;
    }
  }
  if (tid == 0) kc[b * NCLS + c] = sticky ? -kept : kept;
}

// ---------------- K5: merge 80 sorted per-class streams -> top-100 ----------------
__global__ __launch_bounds__(128) void k_merge(const float* boxes, const float* keptScore,
                                               const int* keptRow, const int* kc, float* out) {
  int b = blockIdx.x;
  int tid = threadIdx.x;
  __shared__ float    s_ks[NCLS * MAXPER];     // 32 KB
  __shared__ uint16_t s_krow[NCLS * MAXPER];   // 16 KB
  __shared__ int s_kc[NCLS];
  __shared__ int s_st[NCLS];                   // sticky: last entry repeats forever
  __shared__ int s_heads[NCLS];
  __shared__ unsigned long long s_part2[2];
  __shared__ int s_pickc[MAXPER];
  __shared__ float s_picks[MAXPER];
  __shared__ uint16_t s_pickr[MAXPER];
  __shared__ int s_n;

  for (int i = tid; i < NCLS; i += 128) {
    int kcv = kc[b * NCLS + i];
    s_kc[i] = (kcv < 0) ? -kcv : kcv;
    s_st[i] = (kcv < 0) ? 1 : 0;
    s_heads[i] = 0;
  }
  __syncthreads();
  for (int i = tid; i < NCLS * MAXPER; i += 128) {
    int c = i / MAXPER, k = i - c * MAXPER;
    if (k < s_kc[c]) {
      s_ks[i] = keptScore[(size_t)b * NCLS * MAXPER + i];
      s_krow[i] = (uint16_t)keptRow[(size_t)b * NCLS * MAXPER + i];
    } else { s_ks[i] = 0.0f; s_krow[i] = 0; }
  }
  if (tid == 0) s_n = 0;
  __syncthreads();

  for (int iter = 0; iter < MAXPER; ++iter) {
    unsigned long long key = 0ull;
    if (tid < NCLS) {
      int h = s_heads[tid];
      if (h < s_kc[tid]) {
        float s = s_ks[tid * MAXPER + h];
        unsigned fi = (unsigned)s_krow[tid * MAXPER + h] * 80u + (unsigned)tid;
        key = ((unsigned long long)__float_as_uint(s) << 32) |
              (unsigned long long)(0xFFFFFFFFu - fi);   // tie -> lower flat index
      }
    }
    #pragma unroll
    for (int o = 32; o > 0; o >>= 1) {
      unsigned long long other = __shfl_xor(key, o, 64);
      key = (other > key) ? other : key;
    }
    if ((tid & 63) == 0) s_part2[tid >> 6] = key;
    __syncthreads();
    if (tid == 0) {
      unsigned long long bk = (s_part2[0] > s_part2[1]) ? s_part2[0] : s_part2[1];
      float bs = __uint_as_float((unsigned)(bk >> 32));
      if (bs > 0.0f) {
        unsigned fi = 0xFFFFFFFFu - (unsigned)(bk & 0xFFFFFFFFull);
        int cpick = (int)(fi % 80u);
        int n = s_n;
        s_pickc[n] = cpick;
        s_picks[n] = bs;
        s_pickr[n] = (uint16_t)(fi / 80u);
        s_n = n + 1;
        int h = s_heads[cpick];
        // sticky stream's last entry repeats forever — never exhaust it
        if (!(s_st[cpick] && h == s_kc[cpick] - 1)) s_heads[cpick] = h + 1;
      }
    }
    __syncthreads();
    if (s_n <= iter) break;  // uniform: all streams exhausted
  }
  __syncthreads();
  int n = s_n;

  // output layout (flat f32): [B] ndet | [B,100,4] boxes | [B,100] scores | [B,100] cls
  if (tid == 0) out[b] = (float)n;
  const int OB = BATCH;                    // 8
  const int OP = OB + BATCH * MAXPER * 4;  // 3208
  const int OS = OP + BATCH * MAXPER;      // 4008
  for (int k = tid; k < MAXPER; k += 128) {
    float bx0 = 0.f, bx1 = 0.f, bx2 = 0.f, bx3 = 0.f, sc = 0.f, cf = -1.0f;
    if (k < n) {
      int row = (int)s_pickr[k];
      const float* bo = boxes + ((size_t)(b * TOPK + row)) * 4;
      bx0 = bo[0]; bx1 = bo[1]; bx2 = bo[2]; bx3 = bo[3];
      sc = s_picks[k];
      cf = (float)s_pickc[k];
    }
    float* po = out + OB + (size_t)(b * MAXPER + k) * 4;
    po[0] = bx0; po[1] = bx1; po[2] = bx2; po[3] = bx3;
    out[OP + b * MAXPER + k] = sc;
    out[OS + b * MAXPER + k] = cf;
  }
}

extern "C" void kernel_launch(void* const* d_in, const int* in_sizes, int n_in,
                              void* d_out, int out_size, void* d_ws, size_t ws_size,
                              hipStream_t stream) {
  InPtrs P;
  for (int l = 0; l < 5; ++l) {
    P.cls[l]  = (const float*)d_in[4 * l + 0];
    P.bbox[l] = (const float*)d_in[4 * l + 1];
    P.shp[l]  = (const float*)d_in[4 * l + 2];
    P.loc[l]  = (const float*)d_in[4 * l + 3];
  }
  float* maxscore  = (float*)d_ws;                          // B*NA
  int*   sel       = (int*)(maxscore + BATCH * NA);         // B*TOPK
  float* boxes     = (float*)(sel + BATCH * TOPK);          // B*TOPK*4
  float* sv        = boxes + BATCH * TOPK * 4;              // B*80*TOPK
  float* keptScore = sv + BATCH * NCLS * TOPK;              // B*80*100
  int*   keptRow   = (int*)(keptScore + BATCH * NCLS * MAXPER);
  int*   kc        = keptRow + BATCH * NCLS * MAXPER;
  float* out = (float*)d_out;

  k_maxscore<<<(BATCH * NA + 255) / 256, 256, 0, stream>>>(P, maxscore);
  k_select<<<BATCH, 1024, 0, stream>>>(maxscore, sel);
  k_gather<<<(BATCH * TOPK + 255) / 256, 256, 0, stream>>>(P, sel, boxes, sv);
  k_nms<<<BATCH * NCLS, 256, 0, stream>>>(boxes, sv, keptScore, keptRow, kc);
  k_merge<<<BATCH, 128, 0, stream>>>(boxes, keptScore, keptRow, kc, out);
}

// Round 3
// 422.607 us; speedup vs baseline: 1.1116x; 1.1116x over previous
//
#include <hip/hip_runtime.h>
#include <stdint.h>

#define NCLS 80
#define BATCH 8
#define NA 20460          // total anchors per image across 5 levels
#define TOPK 1000
#define MAXPER 100
#define IMG_WF 1280.0f
#define IMG_HF 768.0f
#define CLS_OFF 4096.0f
#define MAX_RATIO_ANCHOR 13.815510557964274f  // |log(1e-6)|
#define MAX_RATIO_BBOX   4.1351665567423557f  // |log(16/1000)|

__constant__ int   c_lvoff[6] = {0, 15360, 19200, 20160, 20400, 20460};
__constant__ int   c_lw[5]    = {160, 80, 40, 20, 10};
__constant__ int   c_lh[5]    = {96, 48, 24, 12, 6};
__constant__ float c_ls[5]    = {8.f, 16.f, 32.f, 64.f, 128.f};

struct InPtrs {
  const float* cls[5];
  const float* bbox[5];
  const float* shp[5];
  const float* loc[5];
};

__device__ __forceinline__ float sigf(float x) { return 1.0f / (1.0f + expf(-x)); }

// ---------------- K1: per-anchor max score (mask applied) ----------------
__global__ __launch_bounds__(256) void k_maxscore(InPtrs P, float* maxscore) {
  int gid = blockIdx.x * 256 + threadIdx.x;
  if (gid >= BATCH * NA) return;
  int b = gid / NA;
  int a = gid - b * NA;
  int l = 0;
  while (a >= c_lvoff[l + 1]) ++l;
  int within = a - c_lvoff[l];
  int W = c_lw[l], H = c_lh[l];
  int hw = H * W;
  int sp = within;
  const float* cls = P.cls[l];
  int base = (b * NCLS) * hw + sp;
  float m = -1e30f;
  for (int c = 0; c < NCLS; ++c) m = fmaxf(m, cls[base + c * hw]);
  float sl = sigf(P.loc[l][b * hw + sp]);
  float score = 0.0f;
  if (sl >= 0.01f) {
    score = sigf(sigf(m));  // monotone: max of double-sigmoid == double-sigmoid of max
  }
  maxscore[gid] = score;
}

// ---------------- K2: exact top-1000 per batch, in top_k order ----------------
// Values held in registers (20/thread); binary search on float bit patterns for
// the boundary V (range-trimmed: nonzero scores lie in (0.5, 0.734)); then
// collect >V, fill ==V ascending-index, bitonic sort by (score desc, idx asc).
__global__ __launch_bounds__(1024) void k_select(const float* maxscore, int* sel) {
  int b = blockIdx.x;
  const unsigned int* ms = (const unsigned int*)(maxscore + (size_t)b * NA);
  int tid = threadIdx.x;
  __shared__ int s_part[16];
  __shared__ int s_bcast;
  __shared__ int s_pos;
  __shared__ int s_scan[1024];
  __shared__ unsigned long long s_keys[1024];

  unsigned v[20];
  #pragma unroll
  for (int k = 0; k < 20; ++k) {
    int i = tid + k * 1024;
    v[k] = (i < NA) ? ms[i] : 0u;
  }

  // count(>= mid) across the block; 3 barriers per call
  auto countGE = [&](unsigned mid) -> int {
    int c = 0;
    #pragma unroll
    for (int k = 0; k < 20; ++k) c += (v[k] >= mid) ? 1 : 0;
    #pragma unroll
    for (int o = 32; o > 0; o >>= 1) c += __shfl_down(c, o, 64);
    if ((tid & 63) == 0) s_part[tid >> 6] = c;
    __syncthreads();
    if (tid == 0) {
      int t = 0;
      for (int w = 0; w < 16; ++w) t += s_part[w];
      s_bcast = t;
    }
    __syncthreads();
    int r = s_bcast;
    __syncthreads();
    return r;
  };

  // any nonzero score = sig(sig(x)) > 0.5 (bits >= 0x3F000001) and < 0.734375
  unsigned lo, hi;
  if (countGE(0x3F000001u) >= TOPK) { lo = 0x3F000001u; hi = 0x3F3C0000u; }
  else                              { lo = 0u;          hi = 1u; }       // V = 0
  while (hi - lo > 1u) {
    unsigned mid = lo + (hi - lo) / 2u;
    if (countGE(mid) >= TOPK) lo = mid; else hi = mid;
  }
  unsigned V = lo;  // bit pattern of the 1000th-largest value

  if (tid == 0) s_pos = 0;
  if (tid < 1024 - TOPK) s_keys[TOPK + tid] = 0ull;  // pads sink to the end
  __syncthreads();
  #pragma unroll
  for (int k = 0; k < 20; ++k) {
    int i = tid + k * 1024;
    if (v[k] > V) {   // count(>V) < 1000 guaranteed
      int p = atomicAdd(&s_pos, 1);
      s_keys[p] = ((unsigned long long)v[k] << 32) |
                  (unsigned long long)(0xFFFFFFFFu - (unsigned)i);
    }
  }
  __syncthreads();
  int ngt = s_pos;
  int need = TOPK - ngt;  // >= 1; filled by ==V in ascending index order
  const int CH = (NA + 1023) / 1024;  // 20, contiguous chunks (L2-hot re-read)
  int i0 = tid * CH, i1 = min(i0 + CH, NA);
  int ceq = 0;
  for (int i = i0; i < i1; ++i) ceq += (ms[i] == V) ? 1 : 0;
  s_scan[tid] = ceq;
  __syncthreads();
  for (int o = 1; o < 1024; o <<= 1) {
    int vv = s_scan[tid];
    int add = (tid >= o) ? s_scan[tid - o] : 0;
    __syncthreads();
    s_scan[tid] = vv + add;
    __syncthreads();
  }
  int r = s_scan[tid] - ceq;  // exclusive prefix = rank of my first ==V element
  for (int i = i0; i < i1 && r < need; ++i) {
    if (ms[i] == V) {
      s_keys[ngt + r] = ((unsigned long long)V << 32) |
                        (unsigned long long)(0xFFFFFFFFu - (unsigned)i);
      ++r;
    }
  }
  __syncthreads();

  // bitonic sort 1024 keys, descending (score desc, then anchor index asc)
  for (unsigned int k = 2; k <= 1024; k <<= 1) {
    for (unsigned int j = k >> 1; j > 0; j >>= 1) {
      unsigned int i = (unsigned int)tid;
      unsigned int l = i ^ j;
      if (l > i) {
        unsigned long long a = s_keys[i], bk = s_keys[l];
        bool swap = ((i & k) == 0) ? (a < bk) : (a > bk);
        if (swap) { s_keys[i] = bk; s_keys[l] = a; }
      }
      __syncthreads();
    }
  }
  if (tid < TOPK) {
    sel[b * TOPK + tid] = (int)(0xFFFFFFFFu - (unsigned)(s_keys[tid] & 0xFFFFFFFFull));
  }
}

// ---------------- K3: decode boxes + 80 class scores, one WAVE per row ----------------
__global__ __launch_bounds__(256) void k_gather(InPtrs P, const int* sel, float* boxes, float* sv) {
  int wid = blockIdx.x * 4 + (threadIdx.x >> 6);
  int lane = threadIdx.x & 63;
  if (wid >= BATCH * TOPK) return;
  int b = wid / TOPK;
  int r = wid - b * TOPK;
  int a = sel[b * TOPK + r];       // uniform -> broadcast load
  int l = 0;
  while (a >= c_lvoff[l + 1]) ++l;
  int within = a - c_lvoff[l];
  int W = c_lw[l], H = c_lh[l];
  int y = within / W, x = within - y * W;
  int hw = H * W;
  int sp = within;
  float stride = c_ls[l];
  float px = (float)x * stride;
  float py = (float)y * stride;
  float pw = 4.0f * stride;

  // guided anchor from shape_pred (delta2bbox, dx=dy=0, no clip) — wave-uniform
  const float* shp = P.shp[l];
  float dws = shp[(b * 2 + 0) * hw + sp];
  float dhs = shp[(b * 2 + 1) * hw + sp];
  dws = fminf(fmaxf(dws, -MAX_RATIO_ANCHOR), MAX_RATIO_ANCHOR);
  dhs = fminf(fmaxf(dhs, -MAX_RATIO_ANCHOR), MAX_RATIO_ANCHOR);
  float gw = pw * expf(dws);
  float gh = pw * expf(dhs);
  float ax1 = px - 0.5f * gw, ax2 = px + 0.5f * gw;
  float ay1 = py - 0.5f * gh, ay2 = py + 0.5f * gh;

  // proposal from bbox_pred (delta2bbox with image clip)
  const float* bb = P.bbox[l];
  float dx = bb[(b * 4 + 0) * hw + sp];
  float dy = bb[(b * 4 + 1) * hw + sp];
  float dw = bb[(b * 4 + 2) * hw + sp];
  float dh = bb[(b * 4 + 3) * hw + sp];
  dw = fminf(fmaxf(dw, -MAX_RATIO_BBOX), MAX_RATIO_BBOX);
  dh = fminf(fmaxf(dh, -MAX_RATIO_BBOX), MAX_RATIO_BBOX);
  float px2 = (ax1 + ax2) * 0.5f, py2 = (ay1 + ay2) * 0.5f;
  float pw2 = ax2 - ax1, ph2 = ay2 - ay1;
  float gx = px2 + pw2 * dx, gy = py2 + ph2 * dy;
  float gw2 = pw2 * expf(dw), gh2 = ph2 * expf(dh);
  float x1 = fminf(fmaxf(gx - 0.5f * gw2, 0.0f), IMG_WF);
  float x2 = fminf(fmaxf(gx + 0.5f * gw2, 0.0f), IMG_WF);
  float y1 = fminf(fmaxf(gy - 0.5f * gh2, 0.0f), IMG_HF);
  float y2 = fminf(fmaxf(gy + 0.5f * gh2, 0.0f), IMG_HF);
  if (lane == 0) {
    float4 st; st.x = x1; st.y = y1; st.z = x2; st.w = y2;
    ((float4*)boxes)[b * TOPK + r] = st;
  }

  // scores: lane -> class (lanes handle c and c+64)
  const float* cls = P.cls[l];
  float sl = sigf(P.loc[l][b * hw + sp]);
  bool mask = (sl >= 0.01f);
  int base = (b * NCLS) * hw + sp;
  for (int c = lane; c < NCLS; c += 64) {
    float vv = 0.0f;
    if (mask) {
      float s2 = sigf(sigf(cls[base + c * hw]));
      vv = (s2 > 0.05f) ? s2 : 0.0f;   // SCORE_THR (strict >)
    }
    sv[((size_t)(b * NCLS + c)) * TOPK + r] = vv;
  }
}

// ---------------- K4: per-(batch,class) greedy NMS, ONE WAVE, no loop barriers ----
// Packed u32 key per entry: live scores sig(sig(x)) in (0.5, 0.734) share float
// bits[31:22]==0x0FC, so key = (score_low22 << 10) | (1023 - row). Live <=> key>=1024.
// kc: +kept normally, -kept when stream ends in an infinitely repeating
// degenerate pick (box that fails to self-suppress).
__global__ __launch_bounds__(64) void k_nms(const float* boxes, const float* sv,
                                            float* keptScore, int* keptRow, int* kc) {
  int bc = blockIdx.x;              // 0..639
  int b = bc / NCLS;
  int c = bc - b * NCLS;
  int lane = threadIdx.x;

  __shared__ float s_x1[1024], s_y1[1024], s_x2[1024], s_y2[1024], s_ar[1024];

  float x1[16], y1[16], x2[16], y2[16], ar[16];
  unsigned key[16];
  float off = (float)c * CLS_OFF;   // exact in f32
  const float* svc = sv + (size_t)(b * NCLS + c) * TOPK;
  #pragma unroll
  for (int j = 0; j < 16; ++j) {
    int row = j * 64 + lane;
    if (row < TOPK) {
      float4 bo = ((const float4*)boxes)[b * TOPK + row];
      // reference computes IoU/areas on OFFSET coords (f32-rounded) — replicate
      float a = bo.x + off, d = bo.y + off, e = bo.z + off, f = bo.w + off;
      x1[j] = a; y1[j] = d; x2[j] = e; y2[j] = f;
      ar[j] = (e - a) * (f - d);
      unsigned bits = __float_as_uint(svc[row]);   // 0 or in [0x3F000001,0x3F3C0000)
      key[j] = ((bits & 0x3FFFFFu) << 10) | (1023u - (unsigned)row);
      s_x1[row] = a; s_y1[row] = d; s_x2[row] = e; s_y2[row] = f; s_ar[row] = ar[j];
    } else {
      x1[j] = y1[j] = x2[j] = y2[j] = ar[j] = 0.0f;
      key[j] = 0u;
    }
  }
  __syncthreads();   // boxes visible in LDS; loop below is barrier-free

  int kept = 0;
  bool sticky = false;
  float* ks = keptScore + (size_t)(b * NCLS + c) * MAXPER;
  int*   kr = keptRow   + (size_t)(b * NCLS + c) * MAXPER;

  for (int iter = 0; iter < MAXPER; ++iter) {
    // argmax: tie (equal score) -> larger (1023-row) -> lower row, as reference
    unsigned k0 = 0u;
    #pragma unroll
    for (int j = 0; j < 16; ++j) k0 = max(k0, key[j]);
    #pragma unroll
    for (int o = 32; o > 0; o >>= 1) {
      unsigned other = (unsigned)__shfl_xor((int)k0, o, 64);
      k0 = max(k0, other);
    }
    if (k0 < 1024u) break;   // no live entries (masked/dead keys are < 1024)
    int brow = 1023 - (int)(k0 & 1023u);
    float bs = __uint_as_float(0x3F000000u | (k0 >> 10));  // exact score bits
    float bx1 = s_x1[brow], by1 = s_y1[brow];              // uniform LDS broadcast
    float bx2 = s_x2[brow], by2 = s_y2[brow], ba = s_ar[brow];
    if (lane == 0) { ks[kept] = bs; kr[kept] = brow; }
    kept++;
    bool alive = false;
    #pragma unroll
    for (int j = 0; j < 16; ++j) {
      int row = j * 64 + lane;
      float ltx = fmaxf(bx1, x1[j]);
      float lty = fmaxf(by1, y1[j]);
      float rbx = fminf(bx2, x2[j]);
      float rby = fminf(by2, y2[j]);
      float w = fmaxf(rbx - ltx, 0.0f);
      float h = fmaxf(rby - lty, 0.0f);
      float inter = w * h;
      float iou = inter / (ba + ar[j] - inter + 1e-6f);   // IEEE div, same order as ref
      if (iou > 0.5f) key[j] = 0u;
      if (row == brow) alive = (key[j] != 0u);
    }
    // Degenerate pick that fails to self-suppress repeats forever in the ref scan
    unsigned long long bl = __ballot(alive);
    if (bl != 0ull) {
      for (int k2 = kept + lane; k2 < MAXPER; k2 += 64) { ks[k2] = bs; kr[k2] = brow; }
      kept = MAXPER;
      sticky = true;
      break;
    }
  }
  if (lane == 0) kc[b * NCLS + c] = sticky ? -kept : kept;
}

// ---------------- K5: merge 80 sorted per-class streams -> top-100, ONE WAVE ----------
__global__ __launch_bounds__(64) void k_merge(const float* boxes, const float* keptScore,
                                              const int* keptRow, const int* kc, float* out) {
  int b = blockIdx.x;
  int lane = threadIdx.x;
  __shared__ float    s_ks[NCLS * MAXPER];     // 32 KB
  __shared__ uint16_t s_krow[NCLS * MAXPER];   // 16 KB
  __shared__ int s_kc[NCLS];
  __shared__ float    s_picks[MAXPER];
  __shared__ uint16_t s_pickr[MAXPER];
  __shared__ uint16_t s_pickc[MAXPER];

  for (int c = lane; c < NCLS; c += 64) s_kc[c] = kc[b * NCLS + c];
  __syncthreads();
  for (int i = lane; i < NCLS * MAXPER; i += 64) {
    int c = i / MAXPER, k = i - c * MAXPER;
    int kcv = s_kc[c];
    int ka = (kcv < 0) ? -kcv : kcv;
    if (k < ka) {
      s_ks[i] = keptScore[(size_t)b * NCLS * MAXPER + i];
      s_krow[i] = (uint16_t)keptRow[(size_t)b * NCLS * MAXPER + i];
    } else { s_ks[i] = 0.0f; s_krow[i] = 0; }
  }
  __syncthreads();

  // per-lane stream state in registers: lane owns classes lane and lane+64
  int c0 = lane, c1 = lane + 64;
  int kc0 = s_kc[c0];           int st0 = (kc0 < 0); kc0 = st0 ? -kc0 : kc0;
  int kc1 = 0, st1 = 0;
  if (c1 < NCLS) { kc1 = s_kc[c1]; st1 = (kc1 < 0); kc1 = st1 ? -kc1 : kc1; }
  int h0 = 0, h1 = 0;
  int n = 0;

  for (int iter = 0; iter < MAXPER; ++iter) {
    unsigned long long key = 0ull;
    if (h0 < kc0) {
      unsigned fi = (unsigned)s_krow[c0 * MAXPER + h0] * 80u + (unsigned)c0;
      key = ((unsigned long long)__float_as_uint(s_ks[c0 * MAXPER + h0]) << 32) |
            (unsigned long long)(0xFFFFFFFFu - fi);     // tie -> lower flat index
    }
    if (h1 < kc1) {
      unsigned fi = (unsigned)s_krow[c1 * MAXPER + h1] * 80u + (unsigned)c1;
      unsigned long long k2 = ((unsigned long long)__float_as_uint(s_ks[c1 * MAXPER + h1]) << 32) |
                              (unsigned long long)(0xFFFFFFFFu - fi);
      key = (k2 > key) ? k2 : key;
    }
    #pragma unroll
    for (int o = 32; o > 0; o >>= 1) {
      unsigned long long other = __shfl_xor(key, o, 64);
      key = (other > key) ? other : key;
    }
    float bs = __uint_as_float((unsigned)(key >> 32));
    if (bs <= 0.0f) break;      // all streams exhausted (uniform)
    unsigned fi = 0xFFFFFFFFu - (unsigned)(key & 0xFFFFFFFFull);
    int cpick = (int)(fi % 80u);
    int row   = (int)(fi / 80u);
    if (lane == 0) { s_picks[n] = bs; s_pickr[n] = (uint16_t)row; s_pickc[n] = (uint16_t)cpick; }
    n++;
    // sticky stream's last entry repeats forever — never exhaust it
    if (cpick == c0)      { if (!(st0 && h0 == kc0 - 1)) h0++; }
    else if (cpick == c1) { if (!(st1 && h1 == kc1 - 1)) h1++; }
  }
  __syncthreads();

  // output layout (flat f32): [B] ndet | [B,100,4] boxes | [B,100] scores | [B,100] cls
  if (lane == 0) out[b] = (float)n;
  const int OB = BATCH;                    // 8
  const int OP = OB + BATCH * MAXPER * 4;  // 3208
  const int OS = OP + BATCH * MAXPER;      // 4008
  for (int k = lane; k < MAXPER; k += 64) {
    float bx0 = 0.f, bx1 = 0.f, bx2 = 0.f, bx3 = 0.f, sc = 0.f, cf = -1.0f;
    if (k < n) {
      int row = (int)s_pickr[k];
      const float* bo = boxes + ((size_t)(b * TOPK + row)) * 4;
      bx0 = bo[0]; bx1 = bo[1]; bx2 = bo[2]; bx3 = bo[3];
      sc = s_picks[k];
      cf = (float)s_pickc[k];
    }
    float* po = out + OB + (size_t)(b * MAXPER + k) * 4;
    po[0] = bx0; po[1] = bx1; po[2] = bx2; po[3] = bx3;
    out[OP + b * MAXPER + k] = sc;
    out[OS + b * MAXPER + k] = cf;
  }
}

extern "C" void kernel_launch(void* const* d_in, const int* in_sizes, int n_in,
                              void* d_out, int out_size, void* d_ws, size_t ws_size,
                              hipStream_t stream) {
  InPtrs P;
  for (int l = 0; l < 5; ++l) {
    P.cls[l]  = (const float*)d_in[4 * l + 0];
    P.bbox[l] = (const float*)d_in[4 * l + 1];
    P.shp[l]  = (const float*)d_in[4 * l + 2];
    P.loc[l]  = (const float*)d_in[4 * l + 3];
  }
  float* maxscore  = (float*)d_ws;                          // B*NA
  int*   sel       = (int*)(maxscore + BATCH * NA);         // B*TOPK
  float* boxes     = (float*)(sel + BATCH * TOPK);          // B*TOPK*4 (16B aligned)
  float* sv        = boxes + BATCH * TOPK * 4;              // B*80*TOPK
  float* keptScore = sv + BATCH * NCLS * TOPK;              // B*80*100
  int*   keptRow   = (int*)(keptScore + BATCH * NCLS * MAXPER);
  int*   kc        = keptRow + BATCH * NCLS * MAXPER;
  float* out = (float*)d_out;

  k_maxscore<<<(BATCH * NA + 255) / 256, 256, 0, stream>>>(P, maxscore);
  k_select<<<BATCH, 1024, 0, stream>>>(maxscore, sel);
  k_gather<<<(BATCH * TOPK + 3) / 4, 256, 0, stream>>>(P, sel, boxes, sv);
  k_nms<<<BATCH * NCLS, 64, 0, stream>>>(boxes, sv, keptScore, keptRow, kc);
  k_merge<<<BATCH, 64, 0, stream>>>(boxes, keptScore, keptRow, kc, out);
}

// Round 4
// 358.528 us; speedup vs baseline: 1.3103x; 1.1787x over previous
//
#include <hip/hip_runtime.h>
#include <stdint.h>

#define NCLS 80
#define BATCH 8
#define NA 20460          // total anchors per image across 5 levels
#define TOPK 1000
#define MAXPER 100
#define IMG_WF 1280.0f
#define IMG_HF 768.0f
#define CLS_OFF 4096.0f
#define MAX_RATIO_ANCHOR 13.815510557964274f  // |log(1e-6)|
#define MAX_RATIO_BBOX   4.1351665567423557f  // |log(16/1000)|

__constant__ int   c_lvoff[6] = {0, 15360, 19200, 20160, 20400, 20460};
__constant__ int   c_lw[5]    = {160, 80, 40, 20, 10};
__constant__ int   c_lh[5]    = {96, 48, 24, 12, 6};
__constant__ float c_ls[5]    = {8.f, 16.f, 32.f, 64.f, 128.f};

struct InPtrs {
  const float* cls[5];
  const float* bbox[5];
  const float* shp[5];
  const float* loc[5];
};

__device__ __forceinline__ float sigf(float x) { return 1.0f / (1.0f + expf(-x)); }

// ---- DPP wave64 reductions (VALU-only: ~8 cyc/step vs ~120 cyc/ds_swizzle) ----
// row_shr:1/2/4/8 then row_bcast15, row_bcast31; result lands in lane 63,
// broadcast to all lanes via readlane (SGPR). Identity supplied via `old` for
// lanes with invalid DPP source (bound_ctrl=false).
#define DPP_STEP_U(op, ctrl, old) \
  t = (unsigned)__builtin_amdgcn_update_dpp((int)(old), (int)v, ctrl, 0xf, 0xf, false); \
  v = op(v, t);

__device__ __forceinline__ unsigned wave_red_max_u32(unsigned v) {
  unsigned t;
  DPP_STEP_U(max, 0x111, 0u) DPP_STEP_U(max, 0x112, 0u) DPP_STEP_U(max, 0x114, 0u)
  DPP_STEP_U(max, 0x118, 0u) DPP_STEP_U(max, 0x142, 0u) DPP_STEP_U(max, 0x143, 0u)
  return (unsigned)__builtin_amdgcn_readlane((int)v, 63);
}
__device__ __forceinline__ unsigned wave_red_min_u32(unsigned v) {
  unsigned t;
  DPP_STEP_U(min, 0x111, 0xFFFFFFFFu) DPP_STEP_U(min, 0x112, 0xFFFFFFFFu)
  DPP_STEP_U(min, 0x114, 0xFFFFFFFFu) DPP_STEP_U(min, 0x118, 0xFFFFFFFFu)
  DPP_STEP_U(min, 0x142, 0xFFFFFFFFu) DPP_STEP_U(min, 0x143, 0xFFFFFFFFu)
  return (unsigned)__builtin_amdgcn_readlane((int)v, 63);
}
__device__ __forceinline__ int wave_red_sum_i32(int v) {
  int t;
  t = __builtin_amdgcn_update_dpp(0, v, 0x111, 0xf, 0xf, false); v += t;
  t = __builtin_amdgcn_update_dpp(0, v, 0x112, 0xf, 0xf, false); v += t;
  t = __builtin_amdgcn_update_dpp(0, v, 0x114, 0xf, 0xf, false); v += t;
  t = __builtin_amdgcn_update_dpp(0, v, 0x118, 0xf, 0xf, false); v += t;
  t = __builtin_amdgcn_update_dpp(0, v, 0x142, 0xf, 0xf, false); v += t;
  t = __builtin_amdgcn_update_dpp(0, v, 0x143, 0xf, 0xf, false); v += t;
  return __builtin_amdgcn_readlane(v, 63);
}

// ---------------- K1: per-anchor max score (mask applied) ----------------
__global__ __launch_bounds__(256) void k_maxscore(InPtrs P, float* maxscore) {
  int gid = blockIdx.x * 256 + threadIdx.x;
  if (gid >= BATCH * NA) return;
  int b = gid / NA;
  int a = gid - b * NA;
  int l = 0;
  while (a >= c_lvoff[l + 1]) ++l;
  int within = a - c_lvoff[l];
  int W = c_lw[l], H = c_lh[l];
  int hw = H * W;
  int sp = within;
  const float* cls = P.cls[l];
  int base = (b * NCLS) * hw + sp;
  float m = -1e30f;
  for (int c = 0; c < NCLS; ++c) m = fmaxf(m, cls[base + c * hw]);
  float sl = sigf(P.loc[l][b * hw + sp]);
  float score = 0.0f;
  if (sl >= 0.01f) {
    score = sigf(sigf(m));  // monotone: max of double-sigmoid == double-sigmoid of max
  }
  maxscore[gid] = score;
}

// ---------------- K2: exact top-1000 per batch, in top_k order ----------------
__global__ __launch_bounds__(1024) void k_select(const float* maxscore, int* sel) {
  int b = blockIdx.x;
  const unsigned int* ms = (const unsigned int*)(maxscore + (size_t)b * NA);
  int tid = threadIdx.x;
  int wv = tid >> 6;
  int lane = tid & 63;
  __shared__ int s_part[2][16];       // parity double-buffered partials
  __shared__ int s_pos;
  __shared__ int s_scan[1024];
  __shared__ unsigned long long s_keys[1024];

  unsigned v[20];
  #pragma unroll
  for (int k = 0; k < 20; ++k) {
    int i = tid + k * 1024;
    v[k] = (i < NA) ? ms[i] : 0u;
  }

  // count(>= mid) across the block; DPP intra-wave sum + 1 barrier
  int par = 0;
  auto countGE = [&](unsigned mid) -> int {
    int c = 0;
    #pragma unroll
    for (int k = 0; k < 20; ++k) c += (v[k] >= mid) ? 1 : 0;
    c = wave_red_sum_i32(c);
    if (lane == 0) s_part[par][wv] = c;
    __syncthreads();
    int tot = 0;
    #pragma unroll
    for (int w = 0; w < 16; ++w) tot += s_part[par][w];  // LDS broadcast reads
    par ^= 1;
    return tot;
  };

  // any nonzero score = sig(sig(x)) > 0.5 (bits >= 0x3F000001) and < 0.734375
  unsigned lo, hi;
  if (countGE(0x3F000001u) >= TOPK) { lo = 0x3F000001u; hi = 0x3F3C0000u; }
  else                              { lo = 0u;          hi = 1u; }       // V = 0
  while (hi - lo > 1u) {
    unsigned mid = lo + (hi - lo) / 2u;
    if (countGE(mid) >= TOPK) lo = mid; else hi = mid;
  }
  unsigned V = lo;  // bit pattern of the 1000th-largest value

  if (tid == 0) s_pos = 0;
  if (tid < 1024 - TOPK) s_keys[TOPK + tid] = 0ull;  // pads sink to the end
  __syncthreads();
  #pragma unroll
  for (int k = 0; k < 20; ++k) {
    int i = tid + k * 1024;
    if (v[k] > V) {   // count(>V) < 1000 guaranteed
      int p = atomicAdd(&s_pos, 1);
      s_keys[p] = ((unsigned long long)v[k] << 32) |
                  (unsigned long long)(0xFFFFFFFFu - (unsigned)i);
    }
  }
  __syncthreads();
  int ngt = s_pos;
  int need = TOPK - ngt;  // >= 1; filled by ==V in ascending index order
  const int CH = (NA + 1023) / 1024;  // 20, contiguous chunks (L2-hot re-read)
  int i0 = tid * CH, i1 = min(i0 + CH, NA);
  int ceq = 0;
  for (int i = i0; i < i1; ++i) ceq += (ms[i] == V) ? 1 : 0;
  s_scan[tid] = ceq;
  __syncthreads();
  for (int o = 1; o < 1024; o <<= 1) {
    int vv = s_scan[tid];
    int add = (tid >= o) ? s_scan[tid - o] : 0;
    __syncthreads();
    s_scan[tid] = vv + add;
    __syncthreads();
  }
  int r = s_scan[tid] - ceq;  // exclusive prefix = rank of my first ==V element
  for (int i = i0; i < i1 && r < need; ++i) {
    if (ms[i] == V) {
      s_keys[ngt + r] = ((unsigned long long)V << 32) |
                        (unsigned long long)(0xFFFFFFFFu - (unsigned)i);
      ++r;
    }
  }
  __syncthreads();

  // bitonic sort 1024 keys, descending (score desc, then anchor index asc)
  for (unsigned int k = 2; k <= 1024; k <<= 1) {
    for (unsigned int j = k >> 1; j > 0; j >>= 1) {
      unsigned int i = (unsigned int)tid;
      unsigned int l = i ^ j;
      if (l > i) {
        unsigned long long a = s_keys[i], bk = s_keys[l];
        bool swap = ((i & k) == 0) ? (a < bk) : (a > bk);
        if (swap) { s_keys[i] = bk; s_keys[l] = a; }
      }
      __syncthreads();
    }
  }
  if (tid < TOPK) {
    sel[b * TOPK + tid] = (int)(0xFFFFFFFFu - (unsigned)(s_keys[tid] & 0xFFFFFFFFull));
  }
}

// ---------------- K3: decode boxes + 80 class scores, one WAVE per row ----------------
__global__ __launch_bounds__(256) void k_gather(InPtrs P, const int* sel, float* boxes, float* sv) {
  int wid = blockIdx.x * 4 + (threadIdx.x >> 6);
  int lane = threadIdx.x & 63;
  if (wid >= BATCH * TOPK) return;
  int b = wid / TOPK;
  int r = wid - b * TOPK;
  int a = sel[b * TOPK + r];       // uniform -> broadcast load
  int l = 0;
  while (a >= c_lvoff[l + 1]) ++l;
  int within = a - c_lvoff[l];
  int W = c_lw[l], H = c_lh[l];
  int y = within / W, x = within - y * W;
  int hw = H * W;
  int sp = within;
  float stride = c_ls[l];
  float px = (float)x * stride;
  float py = (float)y * stride;
  float pw = 4.0f * stride;

  // guided anchor from shape_pred (delta2bbox, dx=dy=0, no clip) — wave-uniform
  const float* shp = P.shp[l];
  float dws = shp[(b * 2 + 0) * hw + sp];
  float dhs = shp[(b * 2 + 1) * hw + sp];
  dws = fminf(fmaxf(dws, -MAX_RATIO_ANCHOR), MAX_RATIO_ANCHOR);
  dhs = fminf(fmaxf(dhs, -MAX_RATIO_ANCHOR), MAX_RATIO_ANCHOR);
  float gw = pw * expf(dws);
  float gh = pw * expf(dhs);
  float ax1 = px - 0.5f * gw, ax2 = px + 0.5f * gw;
  float ay1 = py - 0.5f * gh, ay2 = py + 0.5f * gh;

  // proposal from bbox_pred (delta2bbox with image clip)
  const float* bb = P.bbox[l];
  float dx = bb[(b * 4 + 0) * hw + sp];
  float dy = bb[(b * 4 + 1) * hw + sp];
  float dw = bb[(b * 4 + 2) * hw + sp];
  float dh = bb[(b * 4 + 3) * hw + sp];
  dw = fminf(fmaxf(dw, -MAX_RATIO_BBOX), MAX_RATIO_BBOX);
  dh = fminf(fmaxf(dh, -MAX_RATIO_BBOX), MAX_RATIO_BBOX);
  float px2 = (ax1 + ax2) * 0.5f, py2 = (ay1 + ay2) * 0.5f;
  float pw2 = ax2 - ax1, ph2 = ay2 - ay1;
  float gx = px2 + pw2 * dx, gy = py2 + ph2 * dy;
  float gw2 = pw2 * expf(dw), gh2 = ph2 * expf(dh);
  float x1 = fminf(fmaxf(gx - 0.5f * gw2, 0.0f), IMG_WF);
  float x2 = fminf(fmaxf(gx + 0.5f * gw2, 0.0f), IMG_WF);
  float y1 = fminf(fmaxf(gy - 0.5f * gh2, 0.0f), IMG_HF);
  float y2 = fminf(fmaxf(gy + 0.5f * gh2, 0.0f), IMG_HF);
  if (lane == 0) {
    float4 st; st.x = x1; st.y = y1; st.z = x2; st.w = y2;
    ((float4*)boxes)[b * TOPK + r] = st;
  }

  // scores: lane -> class (lanes handle c and c+64)
  const float* cls = P.cls[l];
  float sl = sigf(P.loc[l][b * hw + sp]);
  bool mask = (sl >= 0.01f);
  int base = (b * NCLS) * hw + sp;
  for (int c = lane; c < NCLS; c += 64) {
    float vv = 0.0f;
    if (mask) {
      float s2 = sigf(sigf(cls[base + c * hw]));
      vv = (s2 > 0.05f) ? s2 : 0.0f;   // SCORE_THR (strict >)
    }
    sv[((size_t)(b * NCLS + c)) * TOPK + r] = vv;
  }
}

// ---------------- K4: per-(batch,class) greedy NMS, ONE WAVE, DPP argmax ----------
// Packed u32 key: live scores sig(sig(x)) in (0.5, 0.734) share float bits[31:22]
// == 0x0FC, so key = (score_low22 << 10) | (1023 - row). Live <=> key >= 1024.
// kc: +kept normally, -kept when stream ends in an infinitely repeating
// degenerate pick (box that fails to self-suppress).
__global__ __launch_bounds__(64) void k_nms(const float* boxes, const float* sv,
                                            float* keptScore, int* keptRow, int* kc) {
  int bc = blockIdx.x;              // 0..639
  int b = bc / NCLS;
  int c = bc - b * NCLS;
  int lane = threadIdx.x;

  __shared__ float4 s_box[TOPK];    // 16 KB (offset coords)
  __shared__ float  s_ar[TOPK];     // 4 KB

  float x1[16], y1[16], x2[16], y2[16], ar[16];
  unsigned key[16];
  float off = (float)c * CLS_OFF;   // exact in f32
  const float* svc = sv + (size_t)(b * NCLS + c) * TOPK;
  #pragma unroll
  for (int j = 0; j < 16; ++j) {
    int row = j * 64 + lane;
    if (row < TOPK) {
      float4 bo = ((const float4*)boxes)[b * TOPK + row];
      // reference computes IoU/areas on OFFSET coords (f32-rounded) — replicate
      float a = bo.x + off, d = bo.y + off, e = bo.z + off, f = bo.w + off;
      x1[j] = a; y1[j] = d; x2[j] = e; y2[j] = f;
      ar[j] = (e - a) * (f - d);
      unsigned bits = __float_as_uint(svc[row]);   // 0 or in [0x3F000001,0x3F3C0000)
      key[j] = ((bits & 0x3FFFFFu) << 10) | (1023u - (unsigned)row);
      float4 sb; sb.x = a; sb.y = d; sb.z = e; sb.w = f;
      s_box[row] = sb; s_ar[row] = ar[j];
    } else {
      x1[j] = y1[j] = x2[j] = y2[j] = ar[j] = 0.0f;
      key[j] = 0u;
    }
  }
  __syncthreads();   // boxes visible in LDS; loop below is barrier-free

  int kept = 0;
  bool sticky = false;
  float* ks = keptScore + (size_t)(b * NCLS + c) * MAXPER;
  int*   kr = keptRow   + (size_t)(b * NCLS + c) * MAXPER;

  for (int iter = 0; iter < MAXPER; ++iter) {
    // local max over 16 regs (tree), then DPP wave-max (VALU-only, no LDS pipe)
    unsigned m0, m1;
    m0 = max(key[0], key[1]);   m1 = max(key[2], key[3]);   m0 = max(m0, m1);
    m1 = max(key[4], key[5]);   m0 = max(m0, m1);
    m1 = max(key[6], key[7]);   m0 = max(m0, m1);
    m1 = max(key[8], key[9]);   m0 = max(m0, m1);
    m1 = max(key[10], key[11]); m0 = max(m0, m1);
    m1 = max(key[12], key[13]); m0 = max(m0, m1);
    m1 = max(key[14], key[15]); m0 = max(m0, m1);
    unsigned k0 = wave_red_max_u32(m0);        // uniform (SGPR)
    if (k0 < 1024u) break;                     // no live entries
    int brow = 1023 - (int)(k0 & 1023u);
    float bs = __uint_as_float(0x3F000000u | (k0 >> 10));  // exact score bits
    float4 bb = s_box[brow];                   // 1× ds_read_b128 broadcast
    float ba = s_ar[brow];
    float bx1 = bb.x, by1 = bb.y, bx2 = bb.z, by2 = bb.w;
    if (lane == 0) { ks[kept] = bs; kr[kept] = brow; }
    kept++;
    // Degenerate pick (fails to self-suppress) repeats forever in the ref scan.
    // Self-IoU path is bitwise ba/(ba+1e-6): inter_self==ba, (2ba-ba)==ba (Sterbenz).
    float selfiou = ba / (ba + 1e-6f);
    if (!(selfiou > 0.5f)) {
      for (int k2 = kept + lane; k2 < MAXPER; k2 += 64) { ks[k2] = bs; kr[k2] = brow; }
      kept = MAXPER;
      sticky = true;
      break;
    }
    #pragma unroll
    for (int j = 0; j < 16; ++j) {
      float ltx = fmaxf(bx1, x1[j]);
      float rbx = fminf(bx2, x2[j]);
      float w = fmaxf(rbx - ltx, 0.0f);
      float lty = fmaxf(by1, y1[j]);
      float rby = fminf(by2, y2[j]);
      float h = fmaxf(rby - lty, 0.0f);
      float inter = w * h;
      float denom = (ba + ar[j] - inter) + 1e-6f;     // ((ba+ar)-inter)+1e-6, as ref
      float iou = inter / denom;                      // IEEE div, same order as ref
      if (iou > 0.5f) key[j] = 0u;
    }
  }
  if (lane == 0) kc[b * NCLS + c] = sticky ? -kept : kept;
}

// ---------------- K5: merge 80 sorted per-class streams -> top-100, ONE WAVE ----------
// Two-phase u32 DPP argmax: max score bits, then min flat-index (row*80+cls)
// among score ties — identical order to the reference's flattened argmax.
__global__ __launch_bounds__(64) void k_merge(const float* boxes, const float* keptScore,
                                              const int* keptRow, const int* kc, float* out) {
  int b = blockIdx.x;
  int lane = threadIdx.x;
  __shared__ float    s_ks[NCLS * MAXPER];     // 32 KB
  __shared__ uint16_t s_krow[NCLS * MAXPER];   // 16 KB
  __shared__ int     s_kc[NCLS];
  __shared__ uint8_t s_st[NCLS];
  __shared__ float    s_picks[MAXPER];
  __shared__ uint16_t s_pickr[MAXPER];
  __shared__ uint16_t s_pickc[MAXPER];

  for (int c = lane; c < NCLS; c += 64) {
    int kcv = kc[b * NCLS + c];
    s_kc[c] = (kcv < 0) ? -kcv : kcv;
    s_st[c] = (kcv < 0) ? 1 : 0;
  }
  __syncthreads();
  for (int i = lane; i < NCLS * MAXPER; i += 64) {
    int c = i / MAXPER, k = i - c * MAXPER;
    if (k < s_kc[c]) {      // only valid region is ever read
      s_ks[i] = keptScore[(size_t)b * NCLS * MAXPER + i];
      s_krow[i] = (uint16_t)keptRow[(size_t)b * NCLS * MAXPER + i];
    }
  }
  __syncthreads();

  // lane owns classes c0=lane, c1=lane+64; candidates cached in registers
  int c0 = lane, c1 = lane + 64;
  int kc0 = s_kc[c0], st0 = s_st[c0];
  int kc1 = 0, st1 = 0;
  if (c1 < NCLS) { kc1 = s_kc[c1]; st1 = s_st[c1]; }
  int h0 = 0, h1 = 0;
  unsigned cs0 = 0u, cf0 = 0u, cs1 = 0u, cf1 = 0u;
  if (kc0 > 0) { cs0 = __float_as_uint(s_ks[c0 * MAXPER]); cf0 = (unsigned)s_krow[c0 * MAXPER] * 80u + (unsigned)c0; }
  if (kc1 > 0) { cs1 = __float_as_uint(s_ks[c1 * MAXPER]); cf1 = (unsigned)s_krow[c1 * MAXPER] * 80u + (unsigned)c1; }
  int n = 0;

  for (int iter = 0; iter < MAXPER; ++iter) {
    unsigned smax = wave_red_max_u32(max(cs0, cs1));  // scores >0.5 -> bits compare == float compare
    if (smax == 0u) break;                            // all streams exhausted (uniform)
    unsigned f = 0xFFFFFFFFu;
    if (cs0 == smax) f = cf0;
    if (cs1 == smax) f = min(f, cf1);
    unsigned fmin = wave_red_min_u32(f);              // lowest flat index among ties
    int cpick = (int)(fmin % 80u);
    int row   = (int)(fmin / 80u);
    if (lane == 0) { s_picks[n] = __uint_as_float(smax); s_pickr[n] = (uint16_t)row; s_pickc[n] = (uint16_t)cpick; }
    n++;
    if (cpick == c0) {
      if (!(st0 && h0 == kc0 - 1)) {   // sticky last entry repeats forever
        ++h0;
        if (h0 < kc0) { cs0 = __float_as_uint(s_ks[c0 * MAXPER + h0]); cf0 = (unsigned)s_krow[c0 * MAXPER + h0] * 80u + (unsigned)c0; }
        else cs0 = 0u;
      }
    } else if (cpick == c1) {
      if (!(st1 && h1 == kc1 - 1)) {
        ++h1;
        if (h1 < kc1) { cs1 = __float_as_uint(s_ks[c1 * MAXPER + h1]); cf1 = (unsigned)s_krow[c1 * MAXPER + h1] * 80u + (unsigned)c1; }
        else cs1 = 0u;
      }
    }
  }
  __syncthreads();

  // output layout (flat f32): [B] ndet | [B,100,4] boxes | [B,100] scores | [B,100] cls
  if (lane == 0) out[b] = (float)n;
  const int OB = BATCH;                    // 8
  const int OP = OB + BATCH * MAXPER * 4;  // 3208
  const int OS = OP + BATCH * MAXPER;      // 4008
  for (int k = lane; k < MAXPER; k += 64) {
    float bx0 = 0.f, bx1 = 0.f, bx2 = 0.f, bx3 = 0.f, sc = 0.f, cf = -1.0f;
    if (k < n) {
      int row = (int)s_pickr[k];
      const float* bo = boxes + ((size_t)(b * TOPK + row)) * 4;
      bx0 = bo[0]; bx1 = bo[1]; bx2 = bo[2]; bx3 = bo[3];
      sc = s_picks[k];
      cf = (float)s_pickc[k];
    }
    float* po = out + OB + (size_t)(b * MAXPER + k) * 4;
    po[0] = bx0; po[1] = bx1; po[2] = bx2; po[3] = bx3;
    out[OP + b * MAXPER + k] = sc;
    out[OS + b * MAXPER + k] = cf;
  }
}

extern "C" void kernel_launch(void* const* d_in, const int* in_sizes, int n_in,
                              void* d_out, int out_size, void* d_ws, size_t ws_size,
                              hipStream_t stream) {
  InPtrs P;
  for (int l = 0; l < 5; ++l) {
    P.cls[l]  = (const float*)d_in[4 * l + 0];
    P.bbox[l] = (const float*)d_in[4 * l + 1];
    P.shp[l]  = (const float*)d_in[4 * l + 2];
    P.loc[l]  = (const float*)d_in[4 * l + 3];
  }
  float* maxscore  = (float*)d_ws;                          // B*NA
  int*   sel       = (int*)(maxscore + BATCH * NA);         // B*TOPK
  float* boxes     = (float*)(sel + BATCH * TOPK);          // B*TOPK*4 (16B aligned)
  float* sv        = boxes + BATCH * TOPK * 4;              // B*80*TOPK
  float* keptScore = sv + BATCH * NCLS * TOPK;              // B*80*100
  int*   keptRow   = (int*)(keptScore + BATCH * NCLS * MAXPER);
  int*   kc        = keptRow + BATCH * NCLS * MAXPER;
  float* out = (float*)d_out;

  k_maxscore<<<(BATCH * NA + 255) / 256, 256, 0, stream>>>(P, maxscore);
  k_select<<<BATCH, 1024, 0, stream>>>(maxscore, sel);
  k_gather<<<(BATCH * TOPK + 3) / 4, 256, 0, stream>>>(P, sel, boxes, sv);
  k_nms<<<BATCH * NCLS, 64, 0, stream>>>(boxes, sv, keptScore, keptRow, kc);
  k_merge<<<BATCH, 64, 0, stream>>>(boxes, keptScore, keptRow, kc, out);
}

// Round 5
// 336.866 us; speedup vs baseline: 1.3945x; 1.0643x over previous
//
#include <hip/hip_runtime.h>
#include <stdint.h>

#define NCLS 80
#define BATCH 8
#define NA 20460          // total anchors per image across 5 levels
#define TOPK 1000
#define MAXPER 100
#define IMG_WF 1280.0f
#define IMG_HF 768.0f
#define CLS_OFF 4096.0f
#define MAX_RATIO_ANCHOR 13.815510557964274f  // |log(1e-6)|
#define MAX_RATIO_BBOX   4.1351665567423557f  // |log(16/1000)|

// RN(a/b) > 0.5  <=>  a > b*(0.5 + 2^-25) as reals (0.5 mantissa even, tie->down).
// b has 24-bit mantissa, K2 has 25 -> product exact in f64; comparison exact.
#define K2_HALF_UP (0.5 + 0x1p-25)

__constant__ int   c_lvoff[6] = {0, 15360, 19200, 20160, 20400, 20460};
__constant__ int   c_lw[5]    = {160, 80, 40, 20, 10};
__constant__ int   c_lh[5]    = {96, 48, 24, 12, 6};
__constant__ float c_ls[5]    = {8.f, 16.f, 32.f, 64.f, 128.f};

struct InPtrs {
  const float* cls[5];
  const float* bbox[5];
  const float* shp[5];
  const float* loc[5];
};

__device__ __forceinline__ float sigf(float x) { return 1.0f / (1.0f + expf(-x)); }

// ---- DPP wave64 reductions (VALU-only) ----
#define DPP_STEP_U(op, ctrl, old) \
  t = (unsigned)__builtin_amdgcn_update_dpp((int)(old), (int)v, ctrl, 0xf, 0xf, false); \
  v = op(v, t);

__device__ __forceinline__ unsigned wave_red_max_u32(unsigned v) {
  unsigned t;
  DPP_STEP_U(max, 0x111, 0u) DPP_STEP_U(max, 0x112, 0u) DPP_STEP_U(max, 0x114, 0u)
  DPP_STEP_U(max, 0x118, 0u) DPP_STEP_U(max, 0x142, 0u) DPP_STEP_U(max, 0x143, 0u)
  return (unsigned)__builtin_amdgcn_readlane((int)v, 63);
}
__device__ __forceinline__ unsigned wave_red_min_u32(unsigned v) {
  unsigned t;
  DPP_STEP_U(min, 0x111, 0xFFFFFFFFu) DPP_STEP_U(min, 0x112, 0xFFFFFFFFu)
  DPP_STEP_U(min, 0x114, 0xFFFFFFFFu) DPP_STEP_U(min, 0x118, 0xFFFFFFFFu)
  DPP_STEP_U(min, 0x142, 0xFFFFFFFFu) DPP_STEP_U(min, 0x143, 0xFFFFFFFFu)
  return (unsigned)__builtin_amdgcn_readlane((int)v, 63);
}
__device__ __forceinline__ int wave_red_sum_i32(int v) {
  int t;
  t = __builtin_amdgcn_update_dpp(0, v, 0x111, 0xf, 0xf, false); v += t;
  t = __builtin_amdgcn_update_dpp(0, v, 0x112, 0xf, 0xf, false); v += t;
  t = __builtin_amdgcn_update_dpp(0, v, 0x114, 0xf, 0xf, false); v += t;
  t = __builtin_amdgcn_update_dpp(0, v, 0x118, 0xf, 0xf, false); v += t;
  t = __builtin_amdgcn_update_dpp(0, v, 0x142, 0xf, 0xf, false); v += t;
  t = __builtin_amdgcn_update_dpp(0, v, 0x143, 0xf, 0xf, false); v += t;
  return __builtin_amdgcn_readlane(v, 63);
}

// ---------------- K1: per-anchor max score (mask applied) ----------------
__global__ __launch_bounds__(256) void k_maxscore(InPtrs P, float* maxscore) {
  int gid = blockIdx.x * 256 + threadIdx.x;
  if (gid >= BATCH * NA) return;
  int b = gid / NA;
  int a = gid - b * NA;
  int l = 0;
  while (a >= c_lvoff[l + 1]) ++l;
  int within = a - c_lvoff[l];
  int W = c_lw[l], H = c_lh[l];
  int hw = H * W;
  int sp = within;
  const float* cls = P.cls[l];
  int base = (b * NCLS) * hw + sp;
  float m = -1e30f;
  for (int c = 0; c < NCLS; ++c) m = fmaxf(m, cls[base + c * hw]);
  float sl = sigf(P.loc[l][b * hw + sp]);
  float score = 0.0f;
  if (sl >= 0.01f) {
    score = sigf(sigf(m));  // monotone: max of double-sigmoid == double-sigmoid of max
  }
  maxscore[gid] = score;
}

// ---------------- K2: exact top-1000 per batch, in top_k order ----------------
__global__ __launch_bounds__(1024) void k_select(const float* maxscore, int* sel) {
  int b = blockIdx.x;
  const unsigned int* ms = (const unsigned int*)(maxscore + (size_t)b * NA);
  int tid = threadIdx.x;
  int wv = tid >> 6;
  int lane = tid & 63;
  __shared__ int s_part[2][16];       // parity double-buffered partials
  __shared__ int s_pos;
  __shared__ int s_scan[1024];
  __shared__ unsigned long long s_keys[1024];

  unsigned v[20];
  #pragma unroll
  for (int k = 0; k < 20; ++k) {
    int i = tid + k * 1024;
    v[k] = (i < NA) ? ms[i] : 0u;
  }

  int par = 0;
  auto countGE = [&](unsigned mid) -> int {
    int c = 0;
    #pragma unroll
    for (int k = 0; k < 20; ++k) c += (v[k] >= mid) ? 1 : 0;
    c = wave_red_sum_i32(c);
    if (lane == 0) s_part[par][wv] = c;
    __syncthreads();
    int tot = 0;
    #pragma unroll
    for (int w = 0; w < 16; ++w) tot += s_part[par][w];
    par ^= 1;
    return tot;
  };

  // any nonzero score = sig(sig(x)) > 0.5 (bits >= 0x3F000001) and < 0.734375
  unsigned lo, hi;
  if (countGE(0x3F000001u) >= TOPK) { lo = 0x3F000001u; hi = 0x3F3C0000u; }
  else                              { lo = 0u;          hi = 1u; }       // V = 0
  while (hi - lo > 1u) {
    unsigned mid = lo + (hi - lo) / 2u;
    if (countGE(mid) >= TOPK) lo = mid; else hi = mid;
  }
  unsigned V = lo;  // bit pattern of the 1000th-largest value

  if (tid == 0) s_pos = 0;
  if (tid < 1024 - TOPK) s_keys[TOPK + tid] = 0ull;  // pads sink to the end
  __syncthreads();
  #pragma unroll
  for (int k = 0; k < 20; ++k) {
    int i = tid + k * 1024;
    if (v[k] > V) {   // count(>V) < 1000 guaranteed
      int p = atomicAdd(&s_pos, 1);
      s_keys[p] = ((unsigned long long)v[k] << 32) |
                  (unsigned long long)(0xFFFFFFFFu - (unsigned)i);
    }
  }
  __syncthreads();
  int ngt = s_pos;
  int need = TOPK - ngt;  // >= 1; filled by ==V in ascending index order
  const int CH = (NA + 1023) / 1024;  // 20, contiguous chunks (L2-hot re-read)
  int i0 = tid * CH, i1 = min(i0 + CH, NA);
  int ceq = 0;
  for (int i = i0; i < i1; ++i) ceq += (ms[i] == V) ? 1 : 0;
  s_scan[tid] = ceq;
  __syncthreads();
  for (int o = 1; o < 1024; o <<= 1) {
    int vv = s_scan[tid];
    int add = (tid >= o) ? s_scan[tid - o] : 0;
    __syncthreads();
    s_scan[tid] = vv + add;
    __syncthreads();
  }
  int r = s_scan[tid] - ceq;  // exclusive prefix = rank of my first ==V element
  for (int i = i0; i < i1 && r < need; ++i) {
    if (ms[i] == V) {
      s_keys[ngt + r] = ((unsigned long long)V << 32) |
                        (unsigned long long)(0xFFFFFFFFu - (unsigned)i);
      ++r;
    }
  }
  __syncthreads();

  // bitonic sort 1024 keys, descending (score desc, then anchor index asc)
  for (unsigned int k = 2; k <= 1024; k <<= 1) {
    for (unsigned int j = k >> 1; j > 0; j >>= 1) {
      unsigned int i = (unsigned int)tid;
      unsigned int l = i ^ j;
      if (l > i) {
        unsigned long long a = s_keys[i], bk = s_keys[l];
        bool swap = ((i & k) == 0) ? (a < bk) : (a > bk);
        if (swap) { s_keys[i] = bk; s_keys[l] = a; }
      }
      __syncthreads();
    }
  }
  if (tid < TOPK) {
    sel[b * TOPK + tid] = (int)(0xFFFFFFFFu - (unsigned)(s_keys[tid] & 0xFFFFFFFFull));
  }
}

// ---------------- K3: decode boxes + 80 class scores, one WAVE per row ----------------
__global__ __launch_bounds__(256) void k_gather(InPtrs P, const int* sel, float* boxes, float* sv) {
  int wid = blockIdx.x * 4 + (threadIdx.x >> 6);
  int lane = threadIdx.x & 63;
  if (wid >= BATCH * TOPK) return;
  int b = wid / TOPK;
  int r = wid - b * TOPK;
  int a = sel[b * TOPK + r];       // uniform -> broadcast load
  int l = 0;
  while (a >= c_lvoff[l + 1]) ++l;
  int within = a - c_lvoff[l];
  int W = c_lw[l], H = c_lh[l];
  int y = within / W, x = within - y * W;
  int hw = H * W;
  int sp = within;
  float stride = c_ls[l];
  float px = (float)x * stride;
  float py = (float)y * stride;
  float pw = 4.0f * stride;

  // guided anchor from shape_pred (delta2bbox, dx=dy=0, no clip) — wave-uniform
  const float* shp = P.shp[l];
  float dws = shp[(b * 2 + 0) * hw + sp];
  float dhs = shp[(b * 2 + 1) * hw + sp];
  dws = fminf(fmaxf(dws, -MAX_RATIO_ANCHOR), MAX_RATIO_ANCHOR);
  dhs = fminf(fmaxf(dhs, -MAX_RATIO_ANCHOR), MAX_RATIO_ANCHOR);
  float gw = pw * expf(dws);
  float gh = pw * expf(dhs);
  float ax1 = px - 0.5f * gw, ax2 = px + 0.5f * gw;
  float ay1 = py - 0.5f * gh, ay2 = py + 0.5f * gh;

  // proposal from bbox_pred (delta2bbox with image clip)
  const float* bb = P.bbox[l];
  float dx = bb[(b * 4 + 0) * hw + sp];
  float dy = bb[(b * 4 + 1) * hw + sp];
  float dw = bb[(b * 4 + 2) * hw + sp];
  float dh = bb[(b * 4 + 3) * hw + sp];
  dw = fminf(fmaxf(dw, -MAX_RATIO_BBOX), MAX_RATIO_BBOX);
  dh = fminf(fmaxf(dh, -MAX_RATIO_BBOX), MAX_RATIO_BBOX);
  float px2 = (ax1 + ax2) * 0.5f, py2 = (ay1 + ay2) * 0.5f;
  float pw2 = ax2 - ax1, ph2 = ay2 - ay1;
  float gx = px2 + pw2 * dx, gy = py2 + ph2 * dy;
  float gw2 = pw2 * expf(dw), gh2 = ph2 * expf(dh);
  float x1 = fminf(fmaxf(gx - 0.5f * gw2, 0.0f), IMG_WF);
  float x2 = fminf(fmaxf(gx + 0.5f * gw2, 0.0f), IMG_WF);
  float y1 = fminf(fmaxf(gy - 0.5f * gh2, 0.0f), IMG_HF);
  float y2 = fminf(fmaxf(gy + 0.5f * gh2, 0.0f), IMG_HF);
  if (lane == 0) {
    float4 st; st.x = x1; st.y = y1; st.z = x2; st.w = y2;
    ((float4*)boxes)[b * TOPK + r] = st;
  }

  // scores: lane -> class (lanes handle c and c+64)
  const float* cls = P.cls[l];
  float sl = sigf(P.loc[l][b * hw + sp]);
  bool mask = (sl >= 0.01f);
  int base = (b * NCLS) * hw + sp;
  for (int c = lane; c < NCLS; c += 64) {
    float vv = 0.0f;
    if (mask) {
      float s2 = sigf(sigf(cls[base + c * hw]));
      vv = (s2 > 0.05f) ? s2 : 0.0f;   // SCORE_THR (strict >)
    }
    sv[((size_t)(b * NCLS + c)) * TOPK + r] = vv;
  }
}

// ---------------- K4: per-(batch,class) greedy NMS, ONE WAVE, division-free ------
// Packed u32 key: live scores sig(sig(x)) in (0.5, 0.734) share float bits[31:22]
// == 0x0FC, so key = (score_low22 << 10) | (1023 - row). Live <=> key >= 1024.
// Suppression decision RN(inter/denom)>0.5 computed EXACTLY as
// (double)inter > (double)denom * (0.5+2^-25) — no division, no VCC serialization.
// Degenerate flag (self-IoU <= 0.5 -> ref re-picks forever) precomputed at load,
// packed into the sign bit of the stored area.
__global__ __launch_bounds__(64) void k_nms(const float* boxes, const float* sv,
                                            float* keptScore, int* keptRow, int* kc) {
  int bc = blockIdx.x;              // 0..639
  int b = bc / NCLS;
  int c = bc - b * NCLS;
  int lane = threadIdx.x;

  __shared__ float4 s_box[TOPK];    // 16 KB (offset coords)
  __shared__ float  s_ard[TOPK];    // 4 KB: |val| = area, sign bit = degenerate

  float x1[16], y1[16], x2[16], y2[16], ar[16];
  unsigned key[16];
  float off = (float)c * CLS_OFF;   // exact in f32
  const float* svc = sv + (size_t)(b * NCLS + c) * TOPK;
  #pragma unroll
  for (int j = 0; j < 16; ++j) {
    int row = j * 64 + lane;
    if (row < TOPK) {
      float4 bo = ((const float4*)boxes)[b * TOPK + row];
      // reference computes IoU/areas on OFFSET coords (f32-rounded) — replicate
      float a = bo.x + off, d = bo.y + off, e = bo.z + off, f = bo.w + off;
      x1[j] = a; y1[j] = d; x2[j] = e; y2[j] = f;
      ar[j] = (e - a) * (f - d);
      unsigned bits = __float_as_uint(svc[row]);   // 0 or in [0x3F000001,0x3F3C0000)
      key[j] = ((bits & 0x3FFFFFu) << 10) | (1023u - (unsigned)row);
      // self-IoU = RN(ar / RN(ar+1e-6)); degenerate <=> !(selfiou > 0.5)
      float sden = ar[j] + 1e-6f;
      bool deg = !((double)ar[j] > (double)sden * K2_HALF_UP);
      float4 sb; sb.x = a; sb.y = d; sb.z = e; sb.w = f;
      s_box[row] = sb;
      s_ard[row] = __uint_as_float(__float_as_uint(ar[j]) | (deg ? 0x80000000u : 0u));
    } else {
      x1[j] = y1[j] = x2[j] = y2[j] = ar[j] = 0.0f;
      key[j] = 0u;
    }
  }
  __syncthreads();   // boxes visible in LDS; loop below is barrier-free

  int kept = 0;
  bool sticky = false;
  float* ks = keptScore + (size_t)(b * NCLS + c) * MAXPER;
  int*   kr = keptRow   + (size_t)(b * NCLS + c) * MAXPER;

  for (int iter = 0; iter < MAXPER; ++iter) {
    // local max over 16 regs (tree), then DPP wave-max (VALU-only)
    unsigned m0, m1;
    m0 = max(key[0], key[1]);   m1 = max(key[2], key[3]);   m0 = max(m0, m1);
    m1 = max(key[4], key[5]);   m0 = max(m0, m1);
    m1 = max(key[6], key[7]);   m0 = max(m0, m1);
    m1 = max(key[8], key[9]);   m0 = max(m0, m1);
    m1 = max(key[10], key[11]); m0 = max(m0, m1);
    m1 = max(key[12], key[13]); m0 = max(m0, m1);
    m1 = max(key[14], key[15]); m0 = max(m0, m1);
    unsigned k0 = wave_red_max_u32(m0);        // uniform (SGPR)
    if (k0 < 1024u) break;                     // no live entries
    int brow = 1023 - (int)(k0 & 1023u);
    float bs = __uint_as_float(0x3F000000u | (k0 >> 10));  // exact score bits
    float4 bb = s_box[brow];                   // ds_read_b128 broadcast
    unsigned au = __float_as_uint(s_ard[brow]);
    bool deg = (au >> 31) != 0u;
    float ba = __uint_as_float(au & 0x7FFFFFFFu);
    if (lane == 0) { ks[kept] = bs; kr[kept] = brow; }
    kept++;
    // Degenerate pick (fails to self-suppress) repeats forever in the ref scan;
    // its suppression of others can't affect output (stream never advances).
    if (deg) {
      for (int k2 = kept + lane; k2 < MAXPER; k2 += 64) { ks[k2] = bs; kr[k2] = brow; }
      kept = MAXPER;
      sticky = true;
      break;
    }
    float bx1 = bb.x, by1 = bb.y, bx2 = bb.z, by2 = bb.w;
    #pragma unroll
    for (int j = 0; j < 16; ++j) {
      float ltx = fmaxf(bx1, x1[j]);
      float rbx = fminf(bx2, x2[j]);
      float w = fmaxf(rbx - ltx, 0.0f);
      float lty = fmaxf(by1, y1[j]);
      float rby = fminf(by2, y2[j]);
      float h = fmaxf(rby - lty, 0.0f);
      float inter = w * h;
      float denom = ((ba + ar[j]) - inter) + 1e-6f;     // ((ba+ar)-inter)+1e-6, as ref
      // exact: RN(inter/denom) > 0.5
      if ((double)inter > (double)denom * K2_HALF_UP) key[j] = 0u;
    }
  }
  if (lane == 0) kc[b * NCLS + c] = sticky ? -kept : kept;
}

// ---------------- K5: merge 80 sorted per-class streams -> top-100, ONE WAVE ----------
// Two-phase u32 DPP argmax (max score bits, then min flat-index among ties).
// Current + next candidate cached per stream so head-advance LDS latency is
// off the serial critical path.
__global__ __launch_bounds__(64) void k_merge(const float* boxes, const float* keptScore,
                                              const int* keptRow, const int* kc, float* out) {
  int b = blockIdx.x;
  int lane = threadIdx.x;
  __shared__ float    s_ks[NCLS * MAXPER];     // 32 KB
  __shared__ uint16_t s_krow[NCLS * MAXPER];   // 16 KB
  __shared__ int     s_kc[NCLS];
  __shared__ uint8_t s_st[NCLS];
  __shared__ float    s_picks[MAXPER];
  __shared__ uint16_t s_pickr[MAXPER];
  __shared__ uint16_t s_pickc[MAXPER];

  for (int c = lane; c < NCLS; c += 64) {
    int kcv = kc[b * NCLS + c];
    s_kc[c] = (kcv < 0) ? -kcv : kcv;
    s_st[c] = (kcv < 0) ? 1 : 0;
  }
  __syncthreads();
  for (int i = lane; i < NCLS * MAXPER; i += 64) {
    int c = i / MAXPER, k = i - c * MAXPER;
    if (k < s_kc[c]) {      // only valid region is ever read
      s_ks[i] = keptScore[(size_t)b * NCLS * MAXPER + i];
      s_krow[i] = (uint16_t)keptRow[(size_t)b * NCLS * MAXPER + i];
    }
  }
  __syncthreads();

  // lane owns classes c0=lane, c1=lane+64; (cur,next) cached in registers
  int c0 = lane, c1 = lane + 64;
  int kc0 = s_kc[c0], st0 = s_st[c0];
  int kc1 = 0, st1 = 0;
  if (c1 < NCLS) { kc1 = s_kc[c1]; st1 = s_st[c1]; }
  int h0 = 0, h1 = 0;
  unsigned cs0 = 0u, cf0 = 0u, ns0 = 0u, nf0 = 0u;
  unsigned cs1 = 0u, cf1 = 0u, ns1 = 0u, nf1 = 0u;
  if (kc0 > 0) { cs0 = __float_as_uint(s_ks[c0 * MAXPER]); cf0 = (unsigned)s_krow[c0 * MAXPER] * 80u + (unsigned)c0; }
  if (kc0 > 1) { ns0 = __float_as_uint(s_ks[c0 * MAXPER + 1]); nf0 = (unsigned)s_krow[c0 * MAXPER + 1] * 80u + (unsigned)c0; }
  if (kc1 > 0) { cs1 = __float_as_uint(s_ks[c1 * MAXPER]); cf1 = (unsigned)s_krow[c1 * MAXPER] * 80u + (unsigned)c1; }
  if (kc1 > 1) { ns1 = __float_as_uint(s_ks[c1 * MAXPER + 1]); nf1 = (unsigned)s_krow[c1 * MAXPER + 1] * 80u + (unsigned)c1; }
  int n = 0;

  for (int iter = 0; iter < MAXPER; ++iter) {
    unsigned smax = wave_red_max_u32(max(cs0, cs1));  // scores >0.5: bit cmp == float cmp
    if (smax == 0u) break;                            // all streams exhausted (uniform)
    unsigned f = 0xFFFFFFFFu;
    if (cs0 == smax) f = cf0;
    if (cs1 == smax) f = min(f, cf1);
    unsigned fmin = wave_red_min_u32(f);              // lowest flat index among ties
    int cpick = (int)(fmin % 80u);
    int row   = (int)(fmin / 80u);
    if (lane == 0) { s_picks[n] = __uint_as_float(smax); s_pickr[n] = (uint16_t)row; s_pickc[n] = (uint16_t)cpick; }
    n++;
    if (cpick == c0) {
      if (!(st0 && h0 == kc0 - 1)) {   // sticky last entry repeats forever
        ++h0; cs0 = ns0; cf0 = nf0;
        int h2 = h0 + 1;
        if (h2 < kc0) { ns0 = __float_as_uint(s_ks[c0 * MAXPER + h2]); nf0 = (unsigned)s_krow[c0 * MAXPER + h2] * 80u + (unsigned)c0; }
        else ns0 = 0u;
      }
    } else if (cpick == c1) {
      if (!(st1 && h1 == kc1 - 1)) {
        ++h1; cs1 = ns1; cf1 = nf1;
        int h2 = h1 + 1;
        if (h2 < kc1) { ns1 = __float_as_uint(s_ks[c1 * MAXPER + h2]); nf1 = (unsigned)s_krow[c1 * MAXPER + h2] * 80u + (unsigned)c1; }
        else ns1 = 0u;
      }
    }
  }
  __syncthreads();

  // output layout (flat f32): [B] ndet | [B,100,4] boxes | [B,100] scores | [B,100] cls
  if (lane == 0) out[b] = (float)n;
  const int OB = BATCH;                    // 8
  const int OP = OB + BATCH * MAXPER * 4;  // 3208
  const int OS = OP + BATCH * MAXPER;      // 4008
  for (int k = lane; k < MAXPER; k += 64) {
    float bx0 = 0.f, bx1 = 0.f, bx2 = 0.f, bx3 = 0.f, sc = 0.f, cf = -1.0f;
    if (k < n) {
      int row = (int)s_pickr[k];
      const float* bo = boxes + ((size_t)(b * TOPK + row)) * 4;
      bx0 = bo[0]; bx1 = bo[1]; bx2 = bo[2]; bx3 = bo[3];
      sc = s_picks[k];
      cf = (float)s_pickc[k];
    }
    float* po = out + OB + (size_t)(b * MAXPER + k) * 4;
    po[0] = bx0; po[1] = bx1; po[2] = bx2; po[3] = bx3;
    out[OP + b * MAXPER + k] = sc;
    out[OS + b * MAXPER + k] = cf;
  }
}

extern "C" void kernel_launch(void* const* d_in, const int* in_sizes, int n_in,
                              void* d_out, int out_size, void* d_ws, size_t ws_size,
                              hipStream_t stream) {
  InPtrs P;
  for (int l = 0; l < 5; ++l) {
    P.cls[l]  = (const float*)d_in[4 * l + 0];
    P.bbox[l] = (const float*)d_in[4 * l + 1];
    P.shp[l]  = (const float*)d_in[4 * l + 2];
    P.loc[l]  = (const float*)d_in[4 * l + 3];
  }
  float* maxscore  = (float*)d_ws;                          // B*NA
  int*   sel       = (int*)(maxscore + BATCH * NA);         // B*TOPK
  float* boxes     = (float*)(sel + BATCH * TOPK);          // B*TOPK*4 (16B aligned)
  float* sv        = boxes + BATCH * TOPK * 4;              // B*80*TOPK
  float* keptScore = sv + BATCH * NCLS * TOPK;              // B*80*100
  int*   keptRow   = (int*)(keptScore + BATCH * NCLS * MAXPER);
  int*   kc        = keptRow + BATCH * NCLS * MAXPER;
  float* out = (float*)d_out;

  k_maxscore<<<(BATCH * NA + 255) / 256, 256, 0, stream>>>(P, maxscore);
  k_select<<<BATCH, 1024, 0, stream>>>(maxscore, sel);
  k_gather<<<(BATCH * TOPK + 3) / 4, 256, 0, stream>>>(P, sel, boxes, sv);
  k_nms<<<BATCH * NCLS, 64, 0, stream>>>(boxes, sv, keptScore, keptRow, kc);
  k_merge<<<BATCH, 64, 0, stream>>>(boxes, keptScore, keptRow, kc, out);
}

// Round 6
// 280.162 us; speedup vs baseline: 1.6768x; 1.2024x over previous
//
#include <hip/hip_runtime.h>
#include <stdint.h>

#define NCLS 80
#define BATCH 8
#define NA 20460          // total anchors per image across 5 levels
#define TOPK 1000
#define MAXPER 100
#define POOL 256          // merge candidate pool (top-100 + tie slack)
#define IMG_WF 1280.0f
#define IMG_HF 768.0f
#define CLS_OFF 4096.0f
#define MAX_RATIO_ANCHOR 13.815510557964274f  // |log(1e-6)|
#define MAX_RATIO_BBOX   4.1351665567423557f  // |log(16/1000)|

// RN(a/b) > 0.5  <=>  a > b*(0.5 + 2^-25) as reals (0.5 mantissa even, tie->down).
// b has 24-bit mantissa, K2 has 25 -> product exact in f64; comparison exact.
#define K2_HALF_UP (0.5 + 0x1p-25)

__constant__ int   c_lvoff[6] = {0, 15360, 19200, 20160, 20400, 20460};
__constant__ int   c_lw[5]    = {160, 80, 40, 20, 10};
__constant__ int   c_lh[5]    = {96, 48, 24, 12, 6};
__constant__ float c_ls[5]    = {8.f, 16.f, 32.f, 64.f, 128.f};

struct InPtrs {
  const float* cls[5];
  const float* bbox[5];
  const float* shp[5];
  const float* loc[5];
};

__device__ __forceinline__ float sigf(float x) { return 1.0f / (1.0f + expf(-x)); }

// ---- DPP wave64 reductions (VALU-only) ----
#define DPP_STEP_U(op, ctrl, old) \
  t = (unsigned)__builtin_amdgcn_update_dpp((int)(old), (int)v, ctrl, 0xf, 0xf, false); \
  v = op(v, t);

__device__ __forceinline__ unsigned wave_red_max_u32(unsigned v) {
  unsigned t;
  DPP_STEP_U(max, 0x111, 0u) DPP_STEP_U(max, 0x112, 0u) DPP_STEP_U(max, 0x114, 0u)
  DPP_STEP_U(max, 0x118, 0u) DPP_STEP_U(max, 0x142, 0u) DPP_STEP_U(max, 0x143, 0u)
  return (unsigned)__builtin_amdgcn_readlane((int)v, 63);
}
__device__ __forceinline__ int wave_red_sum_i32(int v) {
  int t;
  t = __builtin_amdgcn_update_dpp(0, v, 0x111, 0xf, 0xf, false); v += t;
  t = __builtin_amdgcn_update_dpp(0, v, 0x112, 0xf, 0xf, false); v += t;
  t = __builtin_amdgcn_update_dpp(0, v, 0x114, 0xf, 0xf, false); v += t;
  t = __builtin_amdgcn_update_dpp(0, v, 0x118, 0xf, 0xf, false); v += t;
  t = __builtin_amdgcn_update_dpp(0, v, 0x142, 0xf, 0xf, false); v += t;
  t = __builtin_amdgcn_update_dpp(0, v, 0x143, 0xf, 0xf, false); v += t;
  return __builtin_amdgcn_readlane(v, 63);
}

// ---------------- K1: per-anchor max score (mask applied) ----------------
__global__ __launch_bounds__(256) void k_maxscore(InPtrs P, float* maxscore) {
  int gid = blockIdx.x * 256 + threadIdx.x;
  if (gid >= BATCH * NA) return;
  int b = gid / NA;
  int a = gid - b * NA;
  int l = 0;
  while (a >= c_lvoff[l + 1]) ++l;
  int within = a - c_lvoff[l];
  int W = c_lw[l], H = c_lh[l];
  int hw = H * W;
  int sp = within;
  const float* cls = P.cls[l];
  int base = (b * NCLS) * hw + sp;
  float m = -1e30f;
  for (int c = 0; c < NCLS; ++c) m = fmaxf(m, cls[base + c * hw]);
  float sl = sigf(P.loc[l][b * hw + sp]);
  float score = 0.0f;
  if (sl >= 0.01f) {
    score = sigf(sigf(m));  // monotone: max of double-sigmoid == double-sigmoid of max
  }
  maxscore[gid] = score;
}

// ---------------- K2: exact top-1000 per batch, in top_k order ----------------
__global__ __launch_bounds__(1024) void k_select(const float* maxscore, int* sel) {
  int b = blockIdx.x;
  const unsigned int* ms = (const unsigned int*)(maxscore + (size_t)b * NA);
  int tid = threadIdx.x;
  int wv = tid >> 6;
  int lane = tid & 63;
  __shared__ int s_part[2][16];       // parity double-buffered partials
  __shared__ int s_pos;
  __shared__ int s_scan[1024];
  __shared__ unsigned long long s_keys[1024];

  unsigned v[20];
  #pragma unroll
  for (int k = 0; k < 20; ++k) {
    int i = tid + k * 1024;
    v[k] = (i < NA) ? ms[i] : 0u;
  }

  int par = 0;
  auto countGE = [&](unsigned mid) -> int {
    int c = 0;
    #pragma unroll
    for (int k = 0; k < 20; ++k) c += (v[k] >= mid) ? 1 : 0;
    c = wave_red_sum_i32(c);
    if (lane == 0) s_part[par][wv] = c;
    __syncthreads();
    int tot = 0;
    #pragma unroll
    for (int w = 0; w < 16; ++w) tot += s_part[par][w];
    par ^= 1;
    return tot;
  };

  // any nonzero score = sig(sig(x)) > 0.5 (bits >= 0x3F000001) and < 0.734375
  unsigned lo, hi;
  if (countGE(0x3F000001u) >= TOPK) { lo = 0x3F000001u; hi = 0x3F3C0000u; }
  else                              { lo = 0u;          hi = 1u; }       // V = 0
  while (hi - lo > 1u) {
    unsigned mid = lo + (hi - lo) / 2u;
    if (countGE(mid) >= TOPK) lo = mid; else hi = mid;
  }
  unsigned V = lo;  // bit pattern of the 1000th-largest value

  if (tid == 0) s_pos = 0;
  if (tid < 1024 - TOPK) s_keys[TOPK + tid] = 0ull;  // pads sink to the end
  __syncthreads();
  #pragma unroll
  for (int k = 0; k < 20; ++k) {
    int i = tid + k * 1024;
    if (v[k] > V) {   // count(>V) < 1000 guaranteed
      int p = atomicAdd(&s_pos, 1);
      s_keys[p] = ((unsigned long long)v[k] << 32) |
                  (unsigned long long)(0xFFFFFFFFu - (unsigned)i);
    }
  }
  __syncthreads();
  int ngt = s_pos;
  int need = TOPK - ngt;  // >= 1; filled by ==V in ascending index order
  const int CH = (NA + 1023) / 1024;  // 20, contiguous chunks (L2-hot re-read)
  int i0 = tid * CH, i1 = min(i0 + CH, NA);
  int ceq = 0;
  for (int i = i0; i < i1; ++i) ceq += (ms[i] == V) ? 1 : 0;
  s_scan[tid] = ceq;
  __syncthreads();
  for (int o = 1; o < 1024; o <<= 1) {
    int vv = s_scan[tid];
    int add = (tid >= o) ? s_scan[tid - o] : 0;
    __syncthreads();
    s_scan[tid] = vv + add;
    __syncthreads();
  }
  int r = s_scan[tid] - ceq;  // exclusive prefix = rank of my first ==V element
  for (int i = i0; i < i1 && r < need; ++i) {
    if (ms[i] == V) {
      s_keys[ngt + r] = ((unsigned long long)V << 32) |
                        (unsigned long long)(0xFFFFFFFFu - (unsigned)i);
      ++r;
    }
  }
  __syncthreads();

  // bitonic sort 1024 keys, descending (score desc, then anchor index asc)
  for (unsigned int k = 2; k <= 1024; k <<= 1) {
    for (unsigned int j = k >> 1; j > 0; j >>= 1) {
      unsigned int i = (unsigned int)tid;
      unsigned int l = i ^ j;
      if (l > i) {
        unsigned long long a = s_keys[i], bk = s_keys[l];
        bool swap = ((i & k) == 0) ? (a < bk) : (a > bk);
        if (swap) { s_keys[i] = bk; s_keys[l] = a; }
      }
      __syncthreads();
    }
  }
  if (tid < TOPK) {
    sel[b * TOPK + tid] = (int)(0xFFFFFFFFu - (unsigned)(s_keys[tid] & 0xFFFFFFFFull));
  }
}

// ---------------- K3: decode boxes + 80 class scores, one WAVE per row ----------------
__global__ __launch_bounds__(256) void k_gather(InPtrs P, const int* sel, float* boxes, float* sv) {
  int wid = blockIdx.x * 4 + (threadIdx.x >> 6);
  int lane = threadIdx.x & 63;
  if (wid >= BATCH * TOPK) return;
  int b = wid / TOPK;
  int r = wid - b * TOPK;
  int a = sel[b * TOPK + r];       // uniform -> broadcast load
  int l = 0;
  while (a >= c_lvoff[l + 1]) ++l;
  int within = a - c_lvoff[l];
  int W = c_lw[l], H = c_lh[l];
  int y = within / W, x = within - y * W;
  int hw = H * W;
  int sp = within;
  float stride = c_ls[l];
  float px = (float)x * stride;
  float py = (float)y * stride;
  float pw = 4.0f * stride;

  // guided anchor from shape_pred (delta2bbox, dx=dy=0, no clip) — wave-uniform
  const float* shp = P.shp[l];
  float dws = shp[(b * 2 + 0) * hw + sp];
  float dhs = shp[(b * 2 + 1) * hw + sp];
  dws = fminf(fmaxf(dws, -MAX_RATIO_ANCHOR), MAX_RATIO_ANCHOR);
  dhs = fminf(fmaxf(dhs, -MAX_RATIO_ANCHOR), MAX_RATIO_ANCHOR);
  float gw = pw * expf(dws);
  float gh = pw * expf(dhs);
  float ax1 = px - 0.5f * gw, ax2 = px + 0.5f * gw;
  float ay1 = py - 0.5f * gh, ay2 = py + 0.5f * gh;

  // proposal from bbox_pred (delta2bbox with image clip)
  const float* bb = P.bbox[l];
  float dx = bb[(b * 4 + 0) * hw + sp];
  float dy = bb[(b * 4 + 1) * hw + sp];
  float dw = bb[(b * 4 + 2) * hw + sp];
  float dh = bb[(b * 4 + 3) * hw + sp];
  dw = fminf(fmaxf(dw, -MAX_RATIO_BBOX), MAX_RATIO_BBOX);
  dh = fminf(fmaxf(dh, -MAX_RATIO_BBOX), MAX_RATIO_BBOX);
  float px2 = (ax1 + ax2) * 0.5f, py2 = (ay1 + ay2) * 0.5f;
  float pw2 = ax2 - ax1, ph2 = ay2 - ay1;
  float gx = px2 + pw2 * dx, gy = py2 + ph2 * dy;
  float gw2 = pw2 * expf(dw), gh2 = ph2 * expf(dh);
  float x1 = fminf(fmaxf(gx - 0.5f * gw2, 0.0f), IMG_WF);
  float x2 = fminf(fmaxf(gx + 0.5f * gw2, 0.0f), IMG_WF);
  float y1 = fminf(fmaxf(gy - 0.5f * gh2, 0.0f), IMG_HF);
  float y2 = fminf(fmaxf(gy + 0.5f * gh2, 0.0f), IMG_HF);
  if (lane == 0) {
    float4 st; st.x = x1; st.y = y1; st.z = x2; st.w = y2;
    ((float4*)boxes)[b * TOPK + r] = st;
  }

  // scores: lane -> class (lanes handle c and c+64)
  const float* cls = P.cls[l];
  float sl = sigf(P.loc[l][b * hw + sp]);
  bool mask = (sl >= 0.01f);
  int base = (b * NCLS) * hw + sp;
  for (int c = lane; c < NCLS; c += 64) {
    float vv = 0.0f;
    if (mask) {
      float s2 = sigf(sigf(cls[base + c * hw]));
      vv = (s2 > 0.05f) ? s2 : 0.0f;   // SCORE_THR (strict >)
    }
    sv[((size_t)(b * NCLS + c)) * TOPK + r] = vv;
  }
}

// ---------------- K4: per-(batch,class) greedy NMS, ONE WAVE, division-free ------
// Packed u32 key: live scores sig(sig(x)) in (0.5, 0.734) share float bits[31:22]
// == 0x0FC, so key = (score_low22 << 10) | (1023 - row). Live <=> key >= 1024.
// Suppression decision RN(inter/denom)>0.5 computed EXACTLY as
// (double)inter > (double)denom * (0.5+2^-25) — no division, no VCC serialization.
// Degenerate flag (self-IoU <= 0.5 -> ref re-picks forever) precomputed at load.
// Sticky streams: kc = -kept (last entry = the infinitely-repeating pick; no
// tail duplication — k_merge handles the repeat semantics via truncation).
__global__ __launch_bounds__(64) void k_nms(const float* boxes, const float* sv,
                                            float* keptScore, int* keptRow, int* kc) {
  int bc = blockIdx.x;              // 0..639
  int b = bc / NCLS;
  int c = bc - b * NCLS;
  int lane = threadIdx.x;

  __shared__ float4 s_box[TOPK];    // 16 KB (offset coords)
  __shared__ float  s_ard[TOPK];    // 4 KB: |val| = area, sign bit = degenerate

  float x1[16], y1[16], x2[16], y2[16], ar[16];
  unsigned key[16];
  float off = (float)c * CLS_OFF;   // exact in f32
  const float* svc = sv + (size_t)(b * NCLS + c) * TOPK;
  #pragma unroll
  for (int j = 0; j < 16; ++j) {
    int row = j * 64 + lane;
    if (row < TOPK) {
      float4 bo = ((const float4*)boxes)[b * TOPK + row];
      // reference computes IoU/areas on OFFSET coords (f32-rounded) — replicate
      float a = bo.x + off, d = bo.y + off, e = bo.z + off, f = bo.w + off;
      x1[j] = a; y1[j] = d; x2[j] = e; y2[j] = f;
      ar[j] = (e - a) * (f - d);
      unsigned bits = __float_as_uint(svc[row]);   // 0 or in [0x3F000001,0x3F3C0000)
      key[j] = ((bits & 0x3FFFFFu) << 10) | (1023u - (unsigned)row);
      // self-IoU = RN(ar / RN(ar+1e-6)); degenerate <=> !(selfiou > 0.5)
      float sden = ar[j] + 1e-6f;
      bool deg = !((double)ar[j] > (double)sden * K2_HALF_UP);
      float4 sb; sb.x = a; sb.y = d; sb.z = e; sb.w = f;
      s_box[row] = sb;
      s_ard[row] = __uint_as_float(__float_as_uint(ar[j]) | (deg ? 0x80000000u : 0u));
    } else {
      x1[j] = y1[j] = x2[j] = y2[j] = ar[j] = 0.0f;
      key[j] = 0u;
    }
  }
  __syncthreads();   // boxes visible in LDS; loop below is barrier-free

  int kept = 0;
  bool sticky = false;
  float* ks = keptScore + (size_t)(b * NCLS + c) * MAXPER;
  int*   kr = keptRow   + (size_t)(b * NCLS + c) * MAXPER;

  for (int iter = 0; iter < MAXPER; ++iter) {
    // local max over 16 regs (tree), then DPP wave-max (VALU-only)
    unsigned m0, m1;
    m0 = max(key[0], key[1]);   m1 = max(key[2], key[3]);   m0 = max(m0, m1);
    m1 = max(key[4], key[5]);   m0 = max(m0, m1);
    m1 = max(key[6], key[7]);   m0 = max(m0, m1);
    m1 = max(key[8], key[9]);   m0 = max(m0, m1);
    m1 = max(key[10], key[11]); m0 = max(m0, m1);
    m1 = max(key[12], key[13]); m0 = max(m0, m1);
    m1 = max(key[14], key[15]); m0 = max(m0, m1);
    unsigned k0 = wave_red_max_u32(m0);        // uniform (SGPR)
    if (k0 < 1024u) break;                     // no live entries
    int brow = 1023 - (int)(k0 & 1023u);
    float bs = __uint_as_float(0x3F000000u | (k0 >> 10));  // exact score bits
    float4 bb = s_box[brow];                   // ds_read_b128 broadcast
    unsigned au = __float_as_uint(s_ard[brow]);
    bool deg = (au >> 31) != 0u;
    float ba = __uint_as_float(au & 0x7FFFFFFFu);
    if (lane == 0) { ks[kept] = bs; kr[kept] = brow; }
    kept++;
    // Degenerate pick (fails to self-suppress) repeats forever in the ref scan;
    // stream ends here with its last entry marked sticky (kc < 0).
    if (deg) { sticky = true; break; }
    float bx1 = bb.x, by1 = bb.y, bx2 = bb.z, by2 = bb.w;
    #pragma unroll
    for (int j = 0; j < 16; ++j) {
      float ltx = fmaxf(bx1, x1[j]);
      float rbx = fminf(bx2, x2[j]);
      float w = fmaxf(rbx - ltx, 0.0f);
      float lty = fmaxf(by1, y1[j]);
      float rby = fminf(by2, y2[j]);
      float h = fmaxf(rby - lty, 0.0f);
      float inter = w * h;
      float denom = ((ba + ar[j]) - inter) + 1e-6f;     // ((ba+ar)-inter)+1e-6, as ref
      // exact: RN(inter/denom) > 0.5
      if ((double)inter > (double)denom * K2_HALF_UP) key[j] = 0u;
    }
  }
  if (lane == 0) kc[b * NCLS + c] = sticky ? -kept : kept;
}

// ---------------- K5: sort-based merge -> top-100 ----------------
// Merge-by-max-head of per-class streams sorted by (score desc, flat asc)
// == global sort of the union by that key (in-stream ties are flat-ascending,
// deeper elements never beat their head). Sticky element: once reached it is
// the min-flat max-score head forever => output = sorted union truncated at
// the first sticky element, padded with it to 100.
// Key: (score_bits << 32) | (0x7FFFFFFF - (flat<<1 | sticky)) — flat-major
// tie order preserved, sticky flag carried in bit 0 (low bit 0 <=> sticky).
__global__ __launch_bounds__(256) void k_merge(const float* boxes, const float* keptScore,
                                               const int* keptRow, const int* kc, float* out) {
  int b = blockIdx.x;
  int tid = threadIdx.x;
  int wv = tid >> 6, lane = tid & 63;
  __shared__ int s_kc[NCLS];
  __shared__ int s_part[2][4];
  __shared__ int s_pos;
  __shared__ int s_sticky;
  __shared__ int s_navail;
  __shared__ unsigned long long s_pool[POOL];   // 2 KB

  for (int c = tid; c < NCLS; c += 256) s_kc[c] = kc[b * NCLS + c];
  if (tid == 0) { s_pos = 0; s_sticky = 0x7FFFFFFF; s_navail = 0; }
  for (int i = tid; i < POOL; i += 256) s_pool[i] = 0ull;
  __syncthreads();

  // load all stream scores into registers (coalesced; invalid -> 0)
  unsigned sc[32];
  #pragma unroll
  for (int s = 0; s < 32; ++s) {
    int i = tid + s * 256;
    unsigned vv = 0u;
    if (i < NCLS * MAXPER) {
      int c = i / MAXPER, k = i - c * MAXPER;
      int kcv = s_kc[c];
      int ka = (kcv < 0) ? -kcv : kcv;
      if (k < ka) vv = __float_as_uint(keptScore[(size_t)b * NCLS * MAXPER + i]);
    }
    sc[s] = vv;
  }

  int par = 0;
  auto countGE = [&](unsigned mid) -> int {
    int c = 0;
    #pragma unroll
    for (int s = 0; s < 32; ++s) c += (sc[s] >= mid) ? 1 : 0;
    c = wave_red_sum_i32(c);
    if (lane == 0) s_part[par][wv] = c;
    __syncthreads();
    int tot = s_part[par][0] + s_part[par][1] + s_part[par][2] + s_part[par][3];
    par ^= 1;
    return tot;
  };

  // all valid scores are sig(sig(x)) in (0.5, 0.734): bits in [0x3F000001, 0x3F3C0000)
  int T = countGE(0x3F000001u);        // total stream entries
  unsigned V = 0x3F000001u;            // pool threshold (all valid if T <= 100)
  if (T > MAXPER) {
    unsigned lo = 0x3F000001u, hi = 0x3F3C0000u;
    while (hi - lo > 1u) {
      unsigned mid = lo + (hi - lo) / 2u;
      if (countGE(mid) >= MAXPER) lo = mid; else hi = mid;
    }
    V = lo;   // count(>=V) >= 100, count(>V) < 100
  }

  // gather candidate pool (>= V). Overflow beyond POOL needs >=157 exact f32
  // score ties at the boundary — not reachable with continuous inputs.
  #pragma unroll
  for (int s = 0; s < 32; ++s) {
    if (sc[s] >= V) {
      int i = tid + s * 256;
      int c = i / MAXPER, k = i - c * MAXPER;
      int kcv = s_kc[c];
      int ka = (kcv < 0) ? -kcv : kcv;
      unsigned st = (kcv < 0 && k == ka - 1) ? 1u : 0u;
      unsigned row = (unsigned)keptRow[(size_t)b * NCLS * MAXPER + i];
      unsigned flat = row * 80u + (unsigned)c;
      int p = atomicAdd(&s_pos, 1);
      if (p < POOL)
        s_pool[p] = ((unsigned long long)sc[s] << 32) |
                    (unsigned long long)(0x7FFFFFFFu - ((flat << 1) | st));
    }
  }
  __syncthreads();

  // bitonic sort POOL u64 keys, descending (zeros sink to the end)
  for (unsigned k = 2; k <= POOL; k <<= 1) {
    for (unsigned j = k >> 1; j > 0; j >>= 1) {
      if (tid < POOL) {
        unsigned i = (unsigned)tid, l = i ^ j;
        if (l > i) {
          unsigned long long a = s_pool[i], bk = s_pool[l];
          bool sw = ((i & k) == 0) ? (a < bk) : (a > bk);
          if (sw) { s_pool[i] = bk; s_pool[l] = a; }
        }
      }
      __syncthreads();
    }
  }

  // first sticky position among the leading valid entries; valid count
  if (tid < MAXPER) {
    unsigned long long key = s_pool[tid];
    if (key != 0ull) {
      atomicAdd(&s_navail, 1);
      if ((((unsigned)key) & 1u) == 0u) atomicMin(&s_sticky, tid);  // low bit 0 <=> sticky
    }
  }
  __syncthreads();
  int navail = s_navail;               // valid entries form a prefix after sort
  int p = s_sticky;
  int n = (p < navail) ? MAXPER : navail;

  // output layout (flat f32): [B] ndet | [B,100,4] boxes | [B,100] scores | [B,100] cls
  if (tid == 0) out[b] = (float)n;
  const int OB = BATCH;                    // 8
  const int OP = OB + BATCH * MAXPER * 4;  // 3208
  const int OS = OP + BATCH * MAXPER;      // 4008
  if (tid < MAXPER) {
    int k = tid;
    float bx0 = 0.f, bx1 = 0.f, bx2 = 0.f, bx3 = 0.f, scf = 0.f, cf = -1.0f;
    if (k < n) {
      int idx = (k > p) ? p : k;           // p == INT_MAX when no sticky -> idx = k
      unsigned long long key = s_pool[idx];
      unsigned flat = (0x7FFFFFFFu - (unsigned)key) >> 1;
      unsigned cls = flat % 80u;
      unsigned row = flat / 80u;
      float4 bo = ((const float4*)boxes)[b * TOPK + row];
      bx0 = bo.x; bx1 = bo.y; bx2 = bo.z; bx3 = bo.w;
      scf = __uint_as_float((unsigned)(key >> 32));
      cf = (float)cls;
    }
    float* po = out + OB + (size_t)(b * MAXPER + k) * 4;
    po[0] = bx0; po[1] = bx1; po[2] = bx2; po[3] = bx3;
    out[OP + b * MAXPER + k] = scf;
    out[OS + b * MAXPER + k] = cf;
  }
}

extern "C" void kernel_launch(void* const* d_in, const int* in_sizes, int n_in,
                              void* d_out, int out_size, void* d_ws, size_t ws_size,
                              hipStream_t stream) {
  InPtrs P;
  for (int l = 0; l < 5; ++l) {
    P.cls[l]  = (const float*)d_in[4 * l + 0];
    P.bbox[l] = (const float*)d_in[4 * l + 1];
    P.shp[l]  = (const float*)d_in[4 * l + 2];
    P.loc[l]  = (const float*)d_in[4 * l + 3];
  }
  float* maxscore  = (float*)d_ws;                          // B*NA
  int*   sel       = (int*)(maxscore + BATCH * NA);         // B*TOPK
  float* boxes     = (float*)(sel + BATCH * TOPK);          // B*TOPK*4 (16B aligned)
  float* sv        = boxes + BATCH * TOPK * 4;              // B*80*TOPK
  float* keptScore = sv + BATCH * NCLS * TOPK;              // B*80*100
  int*   keptRow   = (int*)(keptScore + BATCH * NCLS * MAXPER);
  int*   kc        = keptRow + BATCH * NCLS * MAXPER;
  float* out = (float*)d_out;

  k_maxscore<<<(BATCH * NA + 255) / 256, 256, 0, stream>>>(P, maxscore);
  k_select<<<BATCH, 1024, 0, stream>>>(maxscore, sel);
  k_gather<<<(BATCH * TOPK + 3) / 4, 256, 0, stream>>>(P, sel, boxes, sv);
  k_nms<<<BATCH * NCLS, 64, 0, stream>>>(boxes, sv, keptScore, keptRow, kc);
  k_merge<<<BATCH, 256, 0, stream>>>(boxes, keptScore, keptRow, kc, out);
}

// Round 7
// 254.309 us; speedup vs baseline: 1.8473x; 1.1017x over previous
//
#include <hip/hip_runtime.h>
#include <stdint.h>

#define NCLS 80
#define BATCH 8
#define NA 20460          // total anchors per image across 5 levels
#define TOPK 1000
#define MAXPER 100
#define POOL 256          // merge candidate pool (top-100 + tie slack)
#define IMG_WF 1280.0f
#define IMG_HF 768.0f
#define CLS_OFF 4096.0f
#define MAX_RATIO_ANCHOR 13.815510557964274f  // |log(1e-6)|
#define MAX_RATIO_BBOX   4.1351665567423557f  // |log(16/1000)|

// RN(a/b) > 0.5  <=>  a > b*(0.5 + 2^-25) as reals (0.5 mantissa even, tie->down).
// b has 24-bit mantissa, K2 has 25 -> product exact in f64; comparison exact.
#define K2_HALF_UP (0.5 + 0x1p-25)

__constant__ int   c_lvoff[6] = {0, 15360, 19200, 20160, 20400, 20460};
__constant__ int   c_lw[5]    = {160, 80, 40, 20, 10};
__constant__ int   c_lh[5]    = {96, 48, 24, 12, 6};
__constant__ float c_ls[5]    = {8.f, 16.f, 32.f, 64.f, 128.f};

struct InPtrs {
  const float* cls[5];
  const float* bbox[5];
  const float* shp[5];
  const float* loc[5];
};

__device__ __forceinline__ float sigf(float x) { return 1.0f / (1.0f + expf(-x)); }

// ---- DPP wave64 reductions (VALU-only) ----
#define DPP_STEP_U(op, ctrl, old) \
  t = (unsigned)__builtin_amdgcn_update_dpp((int)(old), (int)v, ctrl, 0xf, 0xf, false); \
  v = op(v, t);

__device__ __forceinline__ unsigned wave_red_max_u32(unsigned v) {
  unsigned t;
  DPP_STEP_U(max, 0x111, 0u) DPP_STEP_U(max, 0x112, 0u) DPP_STEP_U(max, 0x114, 0u)
  DPP_STEP_U(max, 0x118, 0u) DPP_STEP_U(max, 0x142, 0u) DPP_STEP_U(max, 0x143, 0u)
  return (unsigned)__builtin_amdgcn_readlane((int)v, 63);
}
__device__ __forceinline__ int wave_red_sum_i32(int v) {
  int t;
  t = __builtin_amdgcn_update_dpp(0, v, 0x111, 0xf, 0xf, false); v += t;
  t = __builtin_amdgcn_update_dpp(0, v, 0x112, 0xf, 0xf, false); v += t;
  t = __builtin_amdgcn_update_dpp(0, v, 0x114, 0xf, 0xf, false); v += t;
  t = __builtin_amdgcn_update_dpp(0, v, 0x118, 0xf, 0xf, false); v += t;
  t = __builtin_amdgcn_update_dpp(0, v, 0x142, 0xf, 0xf, false); v += t;
  t = __builtin_amdgcn_update_dpp(0, v, 0x143, 0xf, 0xf, false); v += t;
  return __builtin_amdgcn_readlane(v, 63);
}

// ---------------- K1: per-anchor max score (mask applied) ----------------
__global__ __launch_bounds__(256) void k_maxscore(InPtrs P, float* maxscore) {
  int gid = blockIdx.x * 256 + threadIdx.x;
  if (gid >= BATCH * NA) return;
  int b = gid / NA;
  int a = gid - b * NA;
  int l = 0;
  while (a >= c_lvoff[l + 1]) ++l;
  int within = a - c_lvoff[l];
  int W = c_lw[l], H = c_lh[l];
  int hw = H * W;
  int sp = within;
  const float* cls = P.cls[l];
  int base = (b * NCLS) * hw + sp;
  float m = -1e30f;
  for (int c = 0; c < NCLS; ++c) m = fmaxf(m, cls[base + c * hw]);
  float sl = sigf(P.loc[l][b * hw + sp]);
  float score = 0.0f;
  if (sl >= 0.01f) {
    score = sigf(sigf(m));  // monotone: max of double-sigmoid == double-sigmoid of max
  }
  maxscore[gid] = score;
}

// ---------------- K2: exact top-1000 per batch, in top_k order ----------------
__global__ __launch_bounds__(1024) void k_select(const float* maxscore, int* sel) {
  int b = blockIdx.x;
  const unsigned int* ms = (const unsigned int*)(maxscore + (size_t)b * NA);
  int tid = threadIdx.x;
  int wv = tid >> 6;
  int lane = tid & 63;
  __shared__ int s_part[2][16];       // parity double-buffered partials
  __shared__ int s_pos;
  __shared__ int s_wtot[16];
  __shared__ unsigned long long s_keys[1024];

  unsigned v[20];
  #pragma unroll
  for (int k = 0; k < 20; ++k) {
    int i = tid + k * 1024;
    v[k] = (i < NA) ? ms[i] : 0u;
  }

  int par = 0;
  auto countGE = [&](unsigned mid) -> int {
    int c = 0;
    #pragma unroll
    for (int k = 0; k < 20; ++k) c += (v[k] >= mid) ? 1 : 0;
    c = wave_red_sum_i32(c);
    if (lane == 0) s_part[par][wv] = c;
    __syncthreads();
    int tot = 0;
    #pragma unroll
    for (int w = 0; w < 16; ++w) tot += s_part[par][w];
    par ^= 1;
    return tot;
  };

  // any nonzero score = sig(sig(x)) > 0.5 (bits >= 0x3F000001) and < 0.734375
  unsigned lo, hi;
  if (countGE(0x3F000001u) >= TOPK) { lo = 0x3F000001u; hi = 0x3F3C0000u; }
  else                              { lo = 0u;          hi = 1u; }       // V = 0
  while (hi - lo > 1u) {
    unsigned mid = lo + (hi - lo) / 2u;
    if (countGE(mid) >= TOPK) lo = mid; else hi = mid;
  }
  unsigned V = lo;  // bit pattern of the 1000th-largest value

  if (tid == 0) s_pos = 0;
  if (tid < 1024 - TOPK) s_keys[TOPK + tid] = 0ull;  // pads sink to the end
  __syncthreads();
  #pragma unroll
  for (int k = 0; k < 20; ++k) {
    int i = tid + k * 1024;
    if (v[k] > V) {   // count(>V) < 1000 guaranteed
      int p = atomicAdd(&s_pos, 1);
      s_keys[p] = ((unsigned long long)v[k] << 32) |
                  (unsigned long long)(0xFFFFFFFFu - (unsigned)i);
    }
  }
  __syncthreads();
  int ngt = s_pos;
  int need = TOPK - ngt;  // >= 1; filled by ==V in ascending index order
  const int CH = (NA + 1023) / 1024;  // 20, contiguous chunks (L2-hot re-read)
  int i0 = tid * CH, i1 = min(i0 + CH, NA);
  int ceq = 0;
  for (int i = i0; i < i1; ++i) ceq += (ms[i] == V) ? 1 : 0;

  // exclusive prefix of ceq over 1024 threads: shfl intra-wave scan + wave offsets
  int incl = ceq;
  #pragma unroll
  for (int o = 1; o < 64; o <<= 1) {
    int u = __shfl_up(incl, o, 64);
    if (lane >= o) incl += u;
  }
  if (lane == 63) s_wtot[wv] = incl;   // wave total
  __syncthreads();
  int woff = 0;
  #pragma unroll
  for (int w = 0; w < 16; ++w) woff += (w < wv) ? s_wtot[w] : 0;
  int r = woff + incl - ceq;           // global exclusive prefix
  for (int i = i0; i < i1 && r < need; ++i) {
    if (ms[i] == V) {
      s_keys[ngt + r] = ((unsigned long long)V << 32) |
                        (unsigned long long)(0xFFFFFFFFu - (unsigned)i);
      ++r;
    }
  }
  __syncthreads();

  // bitonic sort 1024 keys, descending (score desc, then anchor index asc)
  for (unsigned int k = 2; k <= 1024; k <<= 1) {
    for (unsigned int j = k >> 1; j > 0; j >>= 1) {
      unsigned int i = (unsigned int)tid;
      unsigned int l = i ^ j;
      if (l > i) {
        unsigned long long a = s_keys[i], bk = s_keys[l];
        bool swap = ((i & k) == 0) ? (a < bk) : (a > bk);
        if (swap) { s_keys[i] = bk; s_keys[l] = a; }
      }
      __syncthreads();
    }
  }
  if (tid < TOPK) {
    sel[b * TOPK + tid] = (int)(0xFFFFFFFFu - (unsigned)(s_keys[tid] & 0xFFFFFFFFull));
  }
}

// ---------------- K3: decode boxes + 80 class scores, one WAVE per row ----------------
__global__ __launch_bounds__(256) void k_gather(InPtrs P, const int* sel, float* boxes, float* sv) {
  int wid = blockIdx.x * 4 + (threadIdx.x >> 6);
  int lane = threadIdx.x & 63;
  if (wid >= BATCH * TOPK) return;
  int b = wid / TOPK;
  int r = wid - b * TOPK;
  int a = sel[b * TOPK + r];       // uniform -> broadcast load
  int l = 0;
  while (a >= c_lvoff[l + 1]) ++l;
  int within = a - c_lvoff[l];
  int W = c_lw[l], H = c_lh[l];
  int y = within / W, x = within - y * W;
  int hw = H * W;
  int sp = within;
  float stride = c_ls[l];
  float px = (float)x * stride;
  float py = (float)y * stride;
  float pw = 4.0f * stride;

  // guided anchor from shape_pred (delta2bbox, dx=dy=0, no clip) — wave-uniform
  const float* shp = P.shp[l];
  float dws = shp[(b * 2 + 0) * hw + sp];
  float dhs = shp[(b * 2 + 1) * hw + sp];
  dws = fminf(fmaxf(dws, -MAX_RATIO_ANCHOR), MAX_RATIO_ANCHOR);
  dhs = fminf(fmaxf(dhs, -MAX_RATIO_ANCHOR), MAX_RATIO_ANCHOR);
  float gw = pw * expf(dws);
  float gh = pw * expf(dhs);
  float ax1 = px - 0.5f * gw, ax2 = px + 0.5f * gw;
  float ay1 = py - 0.5f * gh, ay2 = py + 0.5f * gh;

  // proposal from bbox_pred (delta2bbox with image clip)
  const float* bb = P.bbox[l];
  float dx = bb[(b * 4 + 0) * hw + sp];
  float dy = bb[(b * 4 + 1) * hw + sp];
  float dw = bb[(b * 4 + 2) * hw + sp];
  float dh = bb[(b * 4 + 3) * hw + sp];
  dw = fminf(fmaxf(dw, -MAX_RATIO_BBOX), MAX_RATIO_BBOX);
  dh = fminf(fmaxf(dh, -MAX_RATIO_BBOX), MAX_RATIO_BBOX);
  float px2 = (ax1 + ax2) * 0.5f, py2 = (ay1 + ay2) * 0.5f;
  float pw2 = ax2 - ax1, ph2 = ay2 - ay1;
  float gx = px2 + pw2 * dx, gy = py2 + ph2 * dy;
  float gw2 = pw2 * expf(dw), gh2 = ph2 * expf(dh);
  float x1 = fminf(fmaxf(gx - 0.5f * gw2, 0.0f), IMG_WF);
  float x2 = fminf(fmaxf(gx + 0.5f * gw2, 0.0f), IMG_WF);
  float y1 = fminf(fmaxf(gy - 0.5f * gh2, 0.0f), IMG_HF);
  float y2 = fminf(fmaxf(gy + 0.5f * gh2, 0.0f), IMG_HF);
  if (lane == 0) {
    float4 st; st.x = x1; st.y = y1; st.z = x2; st.w = y2;
    ((float4*)boxes)[b * TOPK + r] = st;
  }

  // scores: lane -> class (lanes handle c and c+64)
  const float* cls = P.cls[l];
  float sl = sigf(P.loc[l][b * hw + sp]);
  bool mask = (sl >= 0.01f);
  int base = (b * NCLS) * hw + sp;
  for (int c = lane; c < NCLS; c += 64) {
    float vv = 0.0f;
    if (mask) {
      float s2 = sigf(sigf(cls[base + c * hw]));
      vv = (s2 > 0.05f) ? s2 : 0.0f;   // SCORE_THR (strict >)
    }
    sv[((size_t)(b * NCLS + c)) * TOPK + r] = vv;
  }
}

// ---------------- K4: per-(batch,class) greedy NMS, FOUR waves, division-free ----
// 4 boxes/lane; per-wave DPP max -> parity-double-buffered LDS partials ->
// one barrier/iter -> uniform combine. Packed u32 key as before.
// Suppression RN(inter/denom)>0.5 computed exactly in f64 (no division).
// Sticky streams: kc = -kept (last entry = infinitely-repeating pick).
__global__ __launch_bounds__(256) void k_nms(const float* boxes, const float* sv,
                                             float* keptScore, int* keptRow, int* kc) {
  int bc = blockIdx.x;              // 0..639
  int b = bc / NCLS;
  int c = bc - b * NCLS;
  int tid = threadIdx.x;
  int wv = tid >> 6, lane = tid & 63;

  __shared__ float4 s_box[TOPK];        // 16 KB (offset coords)
  __shared__ float  s_ard[TOPK];        // 4 KB: |val| = area, sign = degenerate
  __shared__ unsigned s_part[2][4];     // parity-buffered per-wave argmax partials

  float x1[4], y1[4], x2[4], y2[4], ar[4];
  unsigned key[4];
  float off = (float)c * CLS_OFF;   // exact in f32
  const float* svc = sv + (size_t)(b * NCLS + c) * TOPK;
  #pragma unroll
  for (int j = 0; j < 4; ++j) {
    int row = j * 256 + tid;
    if (row < TOPK) {
      float4 bo = ((const float4*)boxes)[b * TOPK + row];
      // reference computes IoU/areas on OFFSET coords (f32-rounded) — replicate
      float a = bo.x + off, d = bo.y + off, e = bo.z + off, f = bo.w + off;
      x1[j] = a; y1[j] = d; x2[j] = e; y2[j] = f;
      ar[j] = (e - a) * (f - d);
      unsigned bits = __float_as_uint(svc[row]);   // 0 or in [0x3F000001,0x3F3C0000)
      key[j] = ((bits & 0x3FFFFFu) << 10) | (1023u - (unsigned)row);
      // self-IoU = RN(ar / RN(ar+1e-6)); degenerate <=> !(selfiou > 0.5)
      float sden = ar[j] + 1e-6f;
      bool deg = !((double)ar[j] > (double)sden * K2_HALF_UP);
      float4 sb; sb.x = a; sb.y = d; sb.z = e; sb.w = f;
      s_box[row] = sb;
      s_ard[row] = __uint_as_float(__float_as_uint(ar[j]) | (deg ? 0x80000000u : 0u));
    } else {
      x1[j] = y1[j] = x2[j] = y2[j] = ar[j] = 0.0f;
      key[j] = 0u;
    }
  }
  __syncthreads();   // boxes + first partials pattern visible

  int kept = 0;
  bool sticky = false;
  float* ks = keptScore + (size_t)(b * NCLS + c) * MAXPER;
  int*   kr = keptRow   + (size_t)(b * NCLS + c) * MAXPER;

  for (int iter = 0; iter < MAXPER; ++iter) {
    int par = iter & 1;
    unsigned m0 = max(max(key[0], key[1]), max(key[2], key[3]));
    unsigned wmax = wave_red_max_u32(m0);       // per-wave max (uniform in wave)
    if (lane == 0) s_part[par][wv] = wmax;
    __syncthreads();                            // ONE barrier per iteration
    unsigned k0 = max(max(s_part[par][0], s_part[par][1]),
                      max(s_part[par][2], s_part[par][3]));   // uniform
    if (k0 < 1024u) break;                      // no live entries
    int brow = 1023 - (int)(k0 & 1023u);
    float bs = __uint_as_float(0x3F000000u | (k0 >> 10));  // exact score bits
    float4 bb = s_box[brow];                    // broadcast ds_read_b128
    unsigned au = __float_as_uint(s_ard[brow]);
    bool deg = (au >> 31) != 0u;
    float ba = __uint_as_float(au & 0x7FFFFFFFu);
    if (tid == 0) { ks[kept] = bs; kr[kept] = brow; }
    kept++;
    // Degenerate pick (fails to self-suppress) repeats forever in the ref scan;
    // stream ends here, last entry marked sticky (kc < 0).
    if (deg) { sticky = true; break; }
    float bx1 = bb.x, by1 = bb.y, bx2 = bb.z, by2 = bb.w;
    #pragma unroll
    for (int j = 0; j < 4; ++j) {
      float ltx = fmaxf(bx1, x1[j]);
      float rbx = fminf(bx2, x2[j]);
      float w = fmaxf(rbx - ltx, 0.0f);
      float lty = fmaxf(by1, y1[j]);
      float rby = fminf(by2, y2[j]);
      float h = fmaxf(rby - lty, 0.0f);
      float inter = w * h;
      float denom = ((ba + ar[j]) - inter) + 1e-6f;     // as reference
      // exact: RN(inter/denom) > 0.5
      if ((double)inter > (double)denom * K2_HALF_UP) key[j] = 0u;
    }
  }
  if (tid == 0) kc[b * NCLS + c] = sticky ? -kept : kept;
}

// ---------------- K5: sort-based merge -> top-100 ----------------
// Global sort of the stream union by (score desc, flat asc) == merge-by-max-head
// (streams are emitted in that order; sticky element repeats forever =>
// truncate at first sticky, pad with it to 100).
__global__ __launch_bounds__(256) void k_merge(const float* boxes, const float* keptScore,
                                               const int* keptRow, const int* kc, float* out) {
  int b = blockIdx.x;
  int tid = threadIdx.x;
  int wv = tid >> 6, lane = tid & 63;
  __shared__ int s_kc[NCLS];
  __shared__ int s_part[2][4];
  __shared__ int s_pos;
  __shared__ int s_sticky;
  __shared__ int s_navail;
  __shared__ unsigned long long s_pool[POOL];   // 2 KB

  for (int c = tid; c < NCLS; c += 256) s_kc[c] = kc[b * NCLS + c];
  if (tid == 0) { s_pos = 0; s_sticky = 0x7FFFFFFF; s_navail = 0; }
  for (int i = tid; i < POOL; i += 256) s_pool[i] = 0ull;
  __syncthreads();

  // load all stream scores into registers (coalesced; invalid -> 0)
  unsigned sc[32];
  #pragma unroll
  for (int s = 0; s < 32; ++s) {
    int i = tid + s * 256;
    unsigned vv = 0u;
    if (i < NCLS * MAXPER) {
      int c = i / MAXPER, k = i - c * MAXPER;
      int kcv = s_kc[c];
      int ka = (kcv < 0) ? -kcv : kcv;
      if (k < ka) vv = __float_as_uint(keptScore[(size_t)b * NCLS * MAXPER + i]);
    }
    sc[s] = vv;
  }

  int par = 0;
  auto countGE = [&](unsigned mid) -> int {
    int c = 0;
    #pragma unroll
    for (int s = 0; s < 32; ++s) c += (sc[s] >= mid) ? 1 : 0;
    c = wave_red_sum_i32(c);
    if (lane == 0) s_part[par][wv] = c;
    __syncthreads();
    int tot = s_part[par][0] + s_part[par][1] + s_part[par][2] + s_part[par][3];
    par ^= 1;
    return tot;
  };

  // all valid scores are sig(sig(x)) in (0.5, 0.734): bits in [0x3F000001, 0x3F3C0000)
  int T = countGE(0x3F000001u);        // total stream entries
  unsigned V = 0x3F000001u;            // pool threshold (all valid if T <= 100)
  if (T > MAXPER) {
    unsigned lo = 0x3F000001u, hi = 0x3F3C0000u;
    while (hi - lo > 1u) {
      unsigned mid = lo + (hi - lo) / 2u;
      if (countGE(mid) >= MAXPER) lo = mid; else hi = mid;
    }
    V = lo;   // count(>=V) >= 100, count(>V) < 100
  }

  // gather candidate pool (>= V). Overflow beyond POOL needs >=157 exact f32
  // score ties at the boundary — not reachable with continuous inputs.
  #pragma unroll
  for (int s = 0; s < 32; ++s) {
    if (sc[s] >= V) {
      int i = tid + s * 256;
      int c = i / MAXPER, k = i - c * MAXPER;
      int kcv = s_kc[c];
      int ka = (kcv < 0) ? -kcv : kcv;
      unsigned st = (kcv < 0 && k == ka - 1) ? 1u : 0u;
      unsigned row = (unsigned)keptRow[(size_t)b * NCLS * MAXPER + i];
      unsigned flat = row * 80u + (unsigned)c;
      int p = atomicAdd(&s_pos, 1);
      if (p < POOL)
        s_pool[p] = ((unsigned long long)sc[s] << 32) |
                    (unsigned long long)(0x7FFFFFFFu - ((flat << 1) | st));
    }
  }
  __syncthreads();

  // bitonic sort POOL u64 keys, descending (zeros sink to the end)
  for (unsigned k = 2; k <= POOL; k <<= 1) {
    for (unsigned j = k >> 1; j > 0; j >>= 1) {
      if (tid < POOL) {
        unsigned i = (unsigned)tid, l = i ^ j;
        if (l > i) {
          unsigned long long a = s_pool[i], bk = s_pool[l];
          bool sw = ((i & k) == 0) ? (a < bk) : (a > bk);
          if (sw) { s_pool[i] = bk; s_pool[l] = a; }
        }
      }
      __syncthreads();
    }
  }

  // first sticky position among the leading valid entries; valid count
  if (tid < MAXPER) {
    unsigned long long key = s_pool[tid];
    if (key != 0ull) {
      atomicAdd(&s_navail, 1);
      if ((((unsigned)key) & 1u) == 0u) atomicMin(&s_sticky, tid);  // low bit 0 <=> sticky
    }
  }
  __syncthreads();
  int navail = s_navail;               // valid entries form a prefix after sort
  int p = s_sticky;
  int n = (p < navail) ? MAXPER : navail;

  // output layout (flat f32): [B] ndet | [B,100,4] boxes | [B,100] scores | [B,100] cls
  if (tid == 0) out[b] = (float)n;
  const int OB = BATCH;                    // 8
  const int OP = OB + BATCH * MAXPER * 4;  // 3208
  const int OS = OP + BATCH * MAXPER;      // 4008
  if (tid < MAXPER) {
    int k = tid;
    float bx0 = 0.f, bx1 = 0.f, bx2 = 0.f, bx3 = 0.f, scf = 0.f, cf = -1.0f;
    if (k < n) {
      int idx = (k > p) ? p : k;           // p == INT_MAX when no sticky -> idx = k
      unsigned long long key = s_pool[idx];
      unsigned flat = (0x7FFFFFFFu - (unsigned)key) >> 1;
      unsigned cls = flat % 80u;
      unsigned row = flat / 80u;
      float4 bo = ((const float4*)boxes)[b * TOPK + row];
      bx0 = bo.x; bx1 = bo.y; bx2 = bo.z; bx3 = bo.w;
      scf = __uint_as_float((unsigned)(key >> 32));
      cf = (float)cls;
    }
    float* po = out + OB + (size_t)(b * MAXPER + k) * 4;
    po[0] = bx0; po[1] = bx1; po[2] = bx2; po[3] = bx3;
    out[OP + b * MAXPER + k] = scf;
    out[OS + b * MAXPER + k] = cf;
  }
}

extern "C" void kernel_launch(void* const* d_in, const int* in_sizes, int n_in,
                              void* d_out, int out_size, void* d_ws, size_t ws_size,
                              hipStream_t stream) {
  InPtrs P;
  for (int l = 0; l < 5; ++l) {
    P.cls[l]  = (const float*)d_in[4 * l + 0];
    P.bbox[l] = (const float*)d_in[4 * l + 1];
    P.shp[l]  = (const float*)d_in[4 * l + 2];
    P.loc[l]  = (const float*)d_in[4 * l + 3];
  }
  float* maxscore  = (float*)d_ws;                          // B*NA
  int*   sel       = (int*)(maxscore + BATCH * NA);         // B*TOPK
  float* boxes     = (float*)(sel + BATCH * TOPK);          // B*TOPK*4 (16B aligned)
  float* sv        = boxes + BATCH * TOPK * 4;              // B*80*TOPK
  float* keptScore = sv + BATCH * NCLS * TOPK;              // B*80*100
  int*   keptRow   = (int*)(keptScore + BATCH * NCLS * MAXPER);
  int*   kc        = keptRow + BATCH * NCLS * MAXPER;
  float* out = (float*)d_out;

  k_maxscore<<<(BATCH * NA + 255) / 256, 256, 0, stream>>>(P, maxscore);
  k_select<<<BATCH, 1024, 0, stream>>>(maxscore, sel);
  k_gather<<<(BATCH * TOPK + 3) / 4, 256, 0, stream>>>(P, sel, boxes, sv);
  k_nms<<<BATCH * NCLS, 256, 0, stream>>>(boxes, sv, keptScore, keptRow, kc);
  k_merge<<<BATCH, 256, 0, stream>>>(boxes, keptScore, keptRow, kc, out);
}